// Round 10
// baseline (511.357 us; speedup 1.0000x reference)
//
#include <hip/hip_runtime.h>
#include <hip/hip_bf16.h>
#include <math.h>

// InternImage DCNv3 block forward — fp32 optimized, round 10.
// r9: 507 us, mlp_k 182 us w/ 4.5M LDS bank conflicts (32-way on h1 writes,
// row stride 16).  r10: h1 stride 17 (conflict-free writes, broadcast reads),
// LN epilogues fused into out_proj GEMM and MLP (11 -> 8 launches, h2/x2
// round-trips eliminated).
// ws (fp32): F0..F3 = N*192 each | Fm = N*96.

#define BATCH 4
#define HH 56
#define WW 56
#define CC 192
#define NPIX (BATCH * HH * WW)   // 12544

__device__ __forceinline__ float gelu_exact(float x) {
    return 0.5f * x * (1.f + erff(x * 0.70710678118654752f));
}

// ---------------- LN over C=192, one wave per pixel, 4 px/block --------------
__global__ __launch_bounds__(256) void ln4_k(const float* __restrict__ X,
        const float* __restrict__ w, const float* __restrict__ b,
        float* __restrict__ out, float eps)
{
    const int pix  = blockIdx.x * 4 + (threadIdx.x >> 6);
    const int lane = threadIdx.x & 63;
    const size_t base = (size_t)pix * CC;
    float v[3];
    #pragma unroll
    for (int i = 0; i < 3; i++) v[i] = X[base + lane + 64 * i];
    float s = v[0] + v[1] + v[2];
    float q = v[0]*v[0] + v[1]*v[1] + v[2]*v[2];
    #pragma unroll
    for (int off = 32; off > 0; off >>= 1) {
        s += __shfl_xor(s, off, 64);
        q += __shfl_xor(q, off, 64);
    }
    const float mu  = s * (1.f / CC);
    const float var = q * (1.f / CC) - mu * mu;
    const float rs  = rsqrtf(var + eps);
    #pragma unroll
    for (int i = 0; i < 3; i++) {
        const int c = lane + 64 * i;
        out[base + c] = (v[i] - mu) * rs * w[c] + b[c];
    }
}

// --------- tiled GEMM: out[N,M] = A[N,192] @ W[192,M] + bias (M<=192) --------
__global__ __launch_bounds__(256) void gemm_k(const float* __restrict__ A,
        const float* __restrict__ W, const float* __restrict__ bias,
        float* __restrict__ out, int M)
{
    __shared__ float As[32][196];
    const int p0    = blockIdx.x * 32;
    const int tid   = threadIdx.x;
    const int pslot = tid >> 6;
    const int cslot = tid & 63;

    for (int idx = tid; idx < 32 * 192; idx += 256) {
        const int r = idx / 192, c = idx - r * 192;
        As[r][c] = A[(size_t)(p0 + r) * 192 + c];
    }
    __syncthreads();

    float acc[8][3];
    #pragma unroll
    for (int j = 0; j < 3; j++) {
        const int m = cslot + 64 * j;
        const float bb = (m < M) ? bias[m] : 0.f;
        #pragma unroll
        for (int p = 0; p < 8; p++) acc[p][j] = bb;
    }

    for (int k = 0; k < 192; k += 4) {
        float wv[4][3];
        #pragma unroll
        for (int kk = 0; kk < 4; kk++)
            #pragma unroll
            for (int j = 0; j < 3; j++) {
                const int m = cslot + 64 * j;
                wv[kk][j] = (m < M) ? W[(size_t)(k + kk) * M + m] : 0.f;
            }
        #pragma unroll
        for (int p = 0; p < 8; p++) {
            const float4 a = *(const float4*)&As[pslot * 8 + p][k];
            #pragma unroll
            for (int j = 0; j < 3; j++)
                acc[p][j] += a.x*wv[0][j] + a.y*wv[1][j] + a.z*wv[2][j] + a.w*wv[3][j];
        }
    }

    #pragma unroll
    for (int j = 0; j < 3; j++) {
        const int m = cslot + 64 * j;
        if (m < M)
            #pragma unroll
            for (int p = 0; p < 8; p++)
                out[(size_t)(p0 + pslot * 8 + p) * M + m] = acc[p][j];
    }
}

// --- out_proj GEMM fused with x2 = x + LN(d, rpn1) and xn2 = LN(x2, norm2) ---
// Wave (pslot) owns 8 pixels x all 192 cols (3 per lane) -> shuffle LN.
__global__ __launch_bounds__(256) void gemm_ln2_k(const float* __restrict__ A,
        const float* __restrict__ W, const float* __restrict__ bias,
        const float* __restrict__ x,
        const float* __restrict__ r1w, const float* __restrict__ r1b,
        const float* __restrict__ n2w, const float* __restrict__ n2b,
        float* __restrict__ x2out, float* __restrict__ xn2out)
{
    __shared__ float As[32][196];
    const int p0    = blockIdx.x * 32;
    const int tid   = threadIdx.x;
    const int pslot = tid >> 6;
    const int cslot = tid & 63;

    for (int idx = tid; idx < 32 * 192; idx += 256) {
        const int r = idx / 192, c = idx - r * 192;
        As[r][c] = A[(size_t)(p0 + r) * 192 + c];
    }
    __syncthreads();

    float acc[8][3];
    #pragma unroll
    for (int j = 0; j < 3; j++) {
        const float bb = bias[cslot + 64 * j];
        #pragma unroll
        for (int p = 0; p < 8; p++) acc[p][j] = bb;
    }

    for (int k = 0; k < 192; k += 4) {
        float wv[4][3];
        #pragma unroll
        for (int kk = 0; kk < 4; kk++)
            #pragma unroll
            for (int j = 0; j < 3; j++)
                wv[kk][j] = W[(size_t)(k + kk) * 192 + cslot + 64 * j];
        #pragma unroll
        for (int p = 0; p < 8; p++) {
            const float4 a = *(const float4*)&As[pslot * 8 + p][k];
            #pragma unroll
            for (int j = 0; j < 3; j++)
                acc[p][j] += a.x*wv[0][j] + a.y*wv[1][j] + a.z*wv[2][j] + a.w*wv[3][j];
        }
    }

    float w1[3], b1[3], w2[3], b2[3];
    #pragma unroll
    for (int j = 0; j < 3; j++) {
        const int c = cslot + 64 * j;
        w1[j] = r1w[c]; b1[j] = r1b[c]; w2[j] = n2w[c]; b2[j] = n2b[c];
    }

    #pragma unroll
    for (int p = 0; p < 8; p++) {
        const size_t row = p0 + pslot * 8 + p;
        float s = acc[p][0] + acc[p][1] + acc[p][2];
        float q = acc[p][0]*acc[p][0] + acc[p][1]*acc[p][1] + acc[p][2]*acc[p][2];
        #pragma unroll
        for (int off = 32; off > 0; off >>= 1) {
            s += __shfl_xor(s, off, 64);
            q += __shfl_xor(q, off, 64);
        }
        const float mu  = s * (1.f / CC);
        const float var = q * (1.f / CC) - mu * mu;
        const float rs  = rsqrtf(var + 1e-5f);
        float x2v[3];
        #pragma unroll
        for (int j = 0; j < 3; j++) {
            const int c = cslot + 64 * j;
            x2v[j] = x[row * CC + c] + (acc[p][j] - mu) * rs * w1[j] + b1[j];
        }
        float s2 = x2v[0] + x2v[1] + x2v[2];
        float q2 = x2v[0]*x2v[0] + x2v[1]*x2v[1] + x2v[2]*x2v[2];
        #pragma unroll
        for (int off = 32; off > 0; off >>= 1) {
            s2 += __shfl_xor(s2, off, 64);
            q2 += __shfl_xor(q2, off, 64);
        }
        const float mu2  = s2 * (1.f / CC);
        const float var2 = q2 * (1.f / CC) - mu2 * mu2;
        const float rs2  = rsqrtf(var2 + 1e-5f);
        #pragma unroll
        for (int j = 0; j < 3; j++) {
            const int c = cslot + 64 * j;
            x2out[row * CC + c]  = x2v[j];
            xn2out[row * CC + c] = (x2v[j] - mu2) * rs2 * w2[j] + b2[j];
        }
    }
}

// ------- fused depthwise 3x3 conv (SAME) + LN(1e-6) + exact GELU -------------
__global__ __launch_bounds__(192) void dwconv_ln_gelu_k(
        const float* __restrict__ xn, const float* __restrict__ dww,
        const float* __restrict__ dwb, const float* __restrict__ lnw,
        const float* __restrict__ lnb, float* __restrict__ x1)
{
    const int pix  = blockIdx.x;
    const int c    = threadIdx.x;
    const int bimg = pix / (HH * WW);
    const int hw   = pix - bimg * HH * WW;
    const int h    = hw / WW;
    const int w    = hw - h * WW;

    float s = dwb[c];
    #pragma unroll
    for (int ky = 0; ky < 3; ky++) {
        const int yy = h + ky - 1;
        if (yy < 0 || yy >= HH) continue;
        #pragma unroll
        for (int kx = 0; kx < 3; kx++) {
            const int xx = w + kx - 1;
            if (xx < 0 || xx >= WW) continue;
            s += xn[((size_t)(bimg * HH + yy) * WW + xx) * CC + c] *
                 dww[(ky * 3 + kx) * CC + c];
        }
    }
    float sm = s, sq = s * s;
    #pragma unroll
    for (int off = 32; off > 0; off >>= 1) {
        sm += __shfl_xor(sm, off, 64);
        sq += __shfl_xor(sq, off, 64);
    }
    __shared__ float red[6];
    const int wid = threadIdx.x >> 6;
    if ((threadIdx.x & 63) == 0) { red[wid] = sm; red[3 + wid] = sq; }
    __syncthreads();
    const float S = red[0] + red[1] + red[2];
    const float Q = red[3] + red[4] + red[5];
    const float mu  = S * (1.f / CC);
    const float var = Q * (1.f / CC) - mu * mu;
    const float rs  = rsqrtf(var + 1e-6f);
    const float y = (s - mu) * rs * lnw[c] + lnb[c];
    x1[(size_t)pix * CC + c] = gelu_exact(y);
}

// ---- fused sampling: softmax(mask logits) + bilinear gather + cfs blend -----
__global__ __launch_bounds__(192) void sample_k(const float* __restrict__ xp,
        const float* __restrict__ x1g, const float* __restrict__ off,
        const float* __restrict__ mlog, const float* __restrict__ cfsw,
        const float* __restrict__ cfsb, float* __restrict__ outb)
{
    __shared__ float x1s[CC];
    __shared__ float offs[CC];
    __shared__ float mls[96];

    const int pix = blockIdx.x;
    const int t   = threadIdx.x;
    const int bimg = pix / (HH * WW);
    const int hw   = pix - bimg * HH * WW;
    const int h    = hw / WW;
    const int w    = hw - h * WW;

    x1s[t]  = x1g[(size_t)pix * CC + t];
    offs[t] = off[(size_t)pix * CC + t];
    if (t < 96) mls[t] = mlog[(size_t)pix * 96 + t];
    __syncthreads();

    const int g = t >> 4;
    const int c = t & 15;

    float lg[8];
    float mx = -1e30f;
    #pragma unroll
    for (int k = 0; k < 8; k++) { lg[k] = mls[g * 8 + k]; mx = fmaxf(mx, lg[k]); }
    float se = 0.f;
    #pragma unroll
    for (int k = 0; k < 8; k++) { lg[k] = expf(lg[k] - mx); se += lg[k]; }
    const float inv = 1.f / se;

    const int GX[8] = {-1, -1, -1, 0, 0, 1, 1, 1};
    const int GY[8] = {-1, 0, 1, -1, 1, -1, 0, 1};
    const size_t imgbase = (size_t)bimg * HH * WW * CC;

    float acc = 0.f;
    #pragma unroll
    for (int k = 0; k < 8; k++) {
        const float px = (float)w + (float)GX[k] + offs[g * 16 + 2 * k];
        const float py = (float)h + (float)GY[k] + offs[g * 16 + 2 * k + 1];
        const float fx = floorf(px), fy = floorf(py);
        const float wx = px - fx,  wy = py - fy;
        const int x0 = (int)fx, y0 = (int)fy;
        float v00 = 0.f, v01 = 0.f, v10 = 0.f, v11 = 0.f;
        if (y0 >= 0 && y0 < HH) {
            if (x0 >= 0 && x0 < WW)         v00 = xp[imgbase + (size_t)(y0 * WW + x0) * CC + t];
            if (x0 + 1 >= 0 && x0 + 1 < WW) v01 = xp[imgbase + (size_t)(y0 * WW + x0 + 1) * CC + t];
        }
        if (y0 + 1 >= 0 && y0 + 1 < HH) {
            if (x0 >= 0 && x0 < WW)         v10 = xp[imgbase + (size_t)((y0 + 1) * WW + x0) * CC + t];
            if (x0 + 1 >= 0 && x0 + 1 < WW) v11 = xp[imgbase + (size_t)((y0 + 1) * WW + x0 + 1) * CC + t];
        }
        const float bil = (1.f - wy) * ((1.f - wx) * v00 + wx * v01)
                        +         wy * ((1.f - wx) * v10 + wx * v11);
        acc += (lg[k] * inv) * bil;
    }

    float part = 0.f;
    #pragma unroll
    for (int j = 0; j < 12; j++)
        part += x1s[c + 16 * j] * cfsw[(size_t)g * CC + c + 16 * j];
    #pragma unroll
    for (int o = 1; o < 16; o <<= 1) part += __shfl_xor(part, o, 64);
    const float cf = 1.f / (1.f + expf(-(part + cfsb[g])));

    const float xpc = xp[(size_t)pix * CC + t];
    outb[(size_t)pix * CC + t] = acc * (1.f - cf) + xpc * cf;
}

// ---- fused MLP + output: out = x2 + LN(gelu(xn2@fc1+b1)@fc2+b2, rpn2) -------
// 16 px/block, 256 thr.  h1 row stride 17 -> conflict-free writes; reads are
// same-address broadcasts.  Wave owns 4 pixels x 192 cols in fc2 -> shuffle LN.
#define MT 16
__global__ __launch_bounds__(256) void mlp_out_k(const float* __restrict__ xn2,
        const float* __restrict__ fc1w, const float* __restrict__ fc1b,
        const float* __restrict__ fc2w, const float* __restrict__ fc2b,
        const float* __restrict__ x2, const float* __restrict__ r2w,
        const float* __restrict__ r2b, float* __restrict__ out)
{
    __shared__ float xs[CC][MT];       // 12 KB, stride 16 (writes i%32 -> free)
    __shared__ float h1[768][MT + 1];  // 51 KB, stride 17 (writes conflict-free)

    const int p0  = blockIdx.x * MT;
    const int tid = threadIdx.x;

    for (int i = tid; i < MT * CC; i += 256) {
        const int p = i & (MT - 1), c = i >> 4;
        xs[c][p] = xn2[(size_t)(p0 + p) * CC + c];
    }
    __syncthreads();

    // ---- fc1 + GELU ----
    {
        float acc[3][MT];
        #pragma unroll
        for (int j = 0; j < 3; j++) {
            const float bb = fc1b[tid + 256 * j];
            #pragma unroll
            for (int p = 0; p < MT; p++) acc[j][p] = bb;
        }
        for (int k = 0; k < CC; k++) {
            const float w0 = fc1w[(size_t)k * 768 + tid];
            const float w1 = fc1w[(size_t)k * 768 + tid + 256];
            const float w2 = fc1w[(size_t)k * 768 + tid + 512];
            float av[MT];
            #pragma unroll
            for (int q = 0; q < 4; q++) {
                const float4 a = *(const float4*)&xs[k][q * 4];   // broadcast
                av[q*4+0] = a.x; av[q*4+1] = a.y; av[q*4+2] = a.z; av[q*4+3] = a.w;
            }
            #pragma unroll
            for (int p = 0; p < MT; p++) {
                acc[0][p] += av[p] * w0;
                acc[1][p] += av[p] * w1;
                acc[2][p] += av[p] * w2;
            }
        }
        #pragma unroll
        for (int j = 0; j < 3; j++)
            #pragma unroll
            for (int p = 0; p < MT; p++)
                h1[tid + 256 * j][p] = gelu_exact(acc[j][p]);
    }
    __syncthreads();

    // ---- fc2 + epilogue ----
    {
        const int c  = tid & 63;        // = lane
        const int pq = tid >> 6;        // = wave id -> pixel quad
        float acc2[3][4];
        #pragma unroll
        for (int j = 0; j < 3; j++) {
            const float bb = fc2b[c + 64 * j];
            #pragma unroll
            for (int p = 0; p < 4; p++) acc2[j][p] = bb;
        }
        for (int k = 0; k < 768; k++) {
            float hv[4];
            #pragma unroll
            for (int p = 0; p < 4; p++) hv[p] = h1[k][pq * 4 + p];  // broadcast
            const float w0 = fc2w[(size_t)k * CC + c];
            const float w1 = fc2w[(size_t)k * CC + c + 64];
            const float w2 = fc2w[(size_t)k * CC + c + 128];
            #pragma unroll
            for (int p = 0; p < 4; p++) {
                acc2[0][p] += hv[p] * w0;
                acc2[1][p] += hv[p] * w1;
                acc2[2][p] += hv[p] * w2;
            }
        }
        float wl[3], bl[3];
        #pragma unroll
        for (int j = 0; j < 3; j++) { wl[j] = r2w[c + 64 * j]; bl[j] = r2b[c + 64 * j]; }
        #pragma unroll
        for (int p = 0; p < 4; p++) {
            const size_t row = p0 + pq * 4 + p;
            float s = acc2[0][p] + acc2[1][p] + acc2[2][p];
            float q = acc2[0][p]*acc2[0][p] + acc2[1][p]*acc2[1][p] + acc2[2][p]*acc2[2][p];
            #pragma unroll
            for (int off = 32; off > 0; off >>= 1) {
                s += __shfl_xor(s, off, 64);
                q += __shfl_xor(q, off, 64);
            }
            const float mu  = s * (1.f / CC);
            const float var = q * (1.f / CC) - mu * mu;
            const float rs  = rsqrtf(var + 1e-5f);
            #pragma unroll
            for (int j = 0; j < 3; j++) {
                const int cc = c + 64 * j;
                out[row * CC + cc] = x2[row * CC + cc]
                                   + (acc2[j][p] - mu) * rs * wl[j] + bl[j];
            }
        }
    }
}

extern "C" void kernel_launch(void* const* d_in, const int* in_sizes, int n_in,
                              void* d_out, int out_size, void* d_ws, size_t ws_size,
                              hipStream_t stream) {
    const float* x      = (const float*)d_in[0];
    const float* n1w    = (const float*)d_in[1];
    const float* n1b    = (const float*)d_in[2];
    const float* n2w    = (const float*)d_in[3];
    const float* n2b    = (const float*)d_in[4];
    const float* rpn1w  = (const float*)d_in[5];
    const float* rpn1b  = (const float*)d_in[6];
    const float* rpn2w  = (const float*)d_in[7];
    const float* rpn2b  = (const float*)d_in[8];
    const float* inpw   = (const float*)d_in[9];
    const float* inpb   = (const float*)d_in[10];
    const float* dww    = (const float*)d_in[11];
    const float* dwb    = (const float*)d_in[12];
    const float* dwlnw  = (const float*)d_in[13];
    const float* dwlnb  = (const float*)d_in[14];
    const float* offw   = (const float*)d_in[15];
    const float* offb   = (const float*)d_in[16];
    const float* maskw  = (const float*)d_in[17];
    const float* maskb  = (const float*)d_in[18];
    const float* cfsw   = (const float*)d_in[19];
    const float* cfsb   = (const float*)d_in[20];
    const float* outpw  = (const float*)d_in[21];
    const float* outpb  = (const float*)d_in[22];
    const float* fc1w   = (const float*)d_in[23];
    const float* fc1b   = (const float*)d_in[24];
    const float* fc2w   = (const float*)d_in[25];
    const float* fc2b   = (const float*)d_in[26];

    const int N = NPIX;                       // 12544
    const size_t NP = (size_t)N * CC;
    float* F0 = (float*)d_ws;                 // xn -> blended
    float* F1 = F0 + NP;                      // xp -> x2
    float* F2 = F1 + NP;                      // off
    float* F3 = F2 + NP;                      // x1 -> xn2
    float* Fm = F3 + NP;                      // mask logits N*96

    const int lnG = N / 4;     // 3136
    const int gmG = N / 32;    // 392

    // 1. xn = LN(x, norm1)                         -> F0
    ln4_k<<<lnG, 256, 0, stream>>>(x, n1w, n1b, F0, 1e-5f);
    // 2. xp = xn @ in_proj + b                     -> F1
    gemm_k<<<gmG, 256, 0, stream>>>(F0, inpw, inpb, F1, CC);
    // 3. x1 = gelu(LN(dwconv(xn), 1e-6))           -> F3
    dwconv_ln_gelu_k<<<N, 192, 0, stream>>>(F0, dww, dwb, dwlnw, dwlnb, F3);
    // 4. off = x1 @ off_w + b                      -> F2
    gemm_k<<<gmG, 256, 0, stream>>>(F3, offw, offb, F2, CC);
    // 5. mask logits = x1 @ mask_w + b             -> Fm
    gemm_k<<<gmG, 256, 0, stream>>>(F3, maskw, maskb, Fm, 96);
    // 6. blended = sample(xp, x1, off, mlog)       -> F0
    sample_k<<<N, 192, 0, stream>>>(F1, F3, F2, Fm, cfsw, cfsb, F0);
    // 7. x2 = x + LN(blended@out_proj+b, rpn1); xn2 = LN(x2, norm2)
    //                                              -> F1 (x2), F3 (xn2)
    gemm_ln2_k<<<gmG, 256, 0, stream>>>(F0, outpw, outpb, x, rpn1w, rpn1b,
                                        n2w, n2b, F1, F3);
    // 8. out = x2 + LN(gelu(xn2@fc1)@fc2, rpn2)    -> d_out
    mlp_out_k<<<N / MT, 256, 0, stream>>>(F3, fc1w, fc1b, fc2w, fc2b,
                                          F1, rpn2w, rpn2b, (float*)d_out);
}

// Round 11
// 429.093 us; speedup vs baseline: 1.1917x; 1.1917x over previous
//
#include <hip/hip_runtime.h>
#include <hip/hip_bf16.h>
#include <math.h>

// InternImage DCNv3 block forward — round 11: MLP on MFMA (bf16 in, fp32 acc).
// r10 post-mortem: conflicts fixed but mlp still 210us — fp32 VALU GEMM is
// latency-bound at 17% occupancy; structural floor ~47us.  MFMA floor ~3us.
// This round: mlp_out_k -> mlp_mfma_k (16x16x32 bf16 MFMA, weights pre-
// transposed to [N][K] bf16 by prep_w_k).  All other kernels = r10 (passing).
// ws: F0..F3 (N*192 fp32) | Fm (N*96 fp32) | fc1wT, fc2wT (bf16).

#define BATCH 4
#define HH 56
#define WW 56
#define CC 192
#define NPIX (BATCH * HH * WW)   // 12544

typedef __hip_bfloat16 bf16;
typedef __attribute__((ext_vector_type(8))) short short8;
typedef __attribute__((ext_vector_type(4))) float float4v;

__device__ __forceinline__ float gelu_exact(float x) {
    return 0.5f * x * (1.f + erff(x * 0.70710678118654752f));
}

// ---------------- LN over C=192, one wave per pixel, 4 px/block --------------
__global__ __launch_bounds__(256) void ln4_k(const float* __restrict__ X,
        const float* __restrict__ w, const float* __restrict__ b,
        float* __restrict__ out, float eps)
{
    const int pix  = blockIdx.x * 4 + (threadIdx.x >> 6);
    const int lane = threadIdx.x & 63;
    const size_t base = (size_t)pix * CC;
    float v[3];
    #pragma unroll
    for (int i = 0; i < 3; i++) v[i] = X[base + lane + 64 * i];
    float s = v[0] + v[1] + v[2];
    float q = v[0]*v[0] + v[1]*v[1] + v[2]*v[2];
    #pragma unroll
    for (int off = 32; off > 0; off >>= 1) {
        s += __shfl_xor(s, off, 64);
        q += __shfl_xor(q, off, 64);
    }
    const float mu  = s * (1.f / CC);
    const float var = q * (1.f / CC) - mu * mu;
    const float rs  = rsqrtf(var + eps);
    #pragma unroll
    for (int i = 0; i < 3; i++) {
        const int c = lane + 64 * i;
        out[base + c] = (v[i] - mu) * rs * w[c] + b[c];
    }
}

// --------- tiled GEMM: out[N,M] = A[N,192] @ W[192,M] + bias (M<=192) --------
__global__ __launch_bounds__(256) void gemm_k(const float* __restrict__ A,
        const float* __restrict__ W, const float* __restrict__ bias,
        float* __restrict__ out, int M)
{
    __shared__ float As[32][196];
    const int p0    = blockIdx.x * 32;
    const int tid   = threadIdx.x;
    const int pslot = tid >> 6;
    const int cslot = tid & 63;

    for (int idx = tid; idx < 32 * 192; idx += 256) {
        const int r = idx / 192, c = idx - r * 192;
        As[r][c] = A[(size_t)(p0 + r) * 192 + c];
    }
    __syncthreads();

    float acc[8][3];
    #pragma unroll
    for (int j = 0; j < 3; j++) {
        const int m = cslot + 64 * j;
        const float bb = (m < M) ? bias[m] : 0.f;
        #pragma unroll
        for (int p = 0; p < 8; p++) acc[p][j] = bb;
    }

    for (int k = 0; k < 192; k += 4) {
        float wv[4][3];
        #pragma unroll
        for (int kk = 0; kk < 4; kk++)
            #pragma unroll
            for (int j = 0; j < 3; j++) {
                const int m = cslot + 64 * j;
                wv[kk][j] = (m < M) ? W[(size_t)(k + kk) * M + m] : 0.f;
            }
        #pragma unroll
        for (int p = 0; p < 8; p++) {
            const float4 a = *(const float4*)&As[pslot * 8 + p][k];
            #pragma unroll
            for (int j = 0; j < 3; j++)
                acc[p][j] += a.x*wv[0][j] + a.y*wv[1][j] + a.z*wv[2][j] + a.w*wv[3][j];
        }
    }

    #pragma unroll
    for (int j = 0; j < 3; j++) {
        const int m = cslot + 64 * j;
        if (m < M)
            #pragma unroll
            for (int p = 0; p < 8; p++)
                out[(size_t)(p0 + pslot * 8 + p) * M + m] = acc[p][j];
    }
}

// --- out_proj GEMM fused with x2 = x + LN(d, rpn1) and xn2 = LN(x2, norm2) ---
__global__ __launch_bounds__(256) void gemm_ln2_k(const float* __restrict__ A,
        const float* __restrict__ W, const float* __restrict__ bias,
        const float* __restrict__ x,
        const float* __restrict__ r1w, const float* __restrict__ r1b,
        const float* __restrict__ n2w, const float* __restrict__ n2b,
        float* __restrict__ x2out, float* __restrict__ xn2out)
{
    __shared__ float As[32][196];
    const int p0    = blockIdx.x * 32;
    const int tid   = threadIdx.x;
    const int pslot = tid >> 6;
    const int cslot = tid & 63;

    for (int idx = tid; idx < 32 * 192; idx += 256) {
        const int r = idx / 192, c = idx - r * 192;
        As[r][c] = A[(size_t)(p0 + r) * 192 + c];
    }
    __syncthreads();

    float acc[8][3];
    #pragma unroll
    for (int j = 0; j < 3; j++) {
        const float bb = bias[cslot + 64 * j];
        #pragma unroll
        for (int p = 0; p < 8; p++) acc[p][j] = bb;
    }

    for (int k = 0; k < 192; k += 4) {
        float wv[4][3];
        #pragma unroll
        for (int kk = 0; kk < 4; kk++)
            #pragma unroll
            for (int j = 0; j < 3; j++)
                wv[kk][j] = W[(size_t)(k + kk) * 192 + cslot + 64 * j];
        #pragma unroll
        for (int p = 0; p < 8; p++) {
            const float4 a = *(const float4*)&As[pslot * 8 + p][k];
            #pragma unroll
            for (int j = 0; j < 3; j++)
                acc[p][j] += a.x*wv[0][j] + a.y*wv[1][j] + a.z*wv[2][j] + a.w*wv[3][j];
        }
    }

    float w1[3], b1[3], w2[3], b2[3];
    #pragma unroll
    for (int j = 0; j < 3; j++) {
        const int c = cslot + 64 * j;
        w1[j] = r1w[c]; b1[j] = r1b[c]; w2[j] = n2w[c]; b2[j] = n2b[c];
    }

    #pragma unroll
    for (int p = 0; p < 8; p++) {
        const size_t row = p0 + pslot * 8 + p;
        float s = acc[p][0] + acc[p][1] + acc[p][2];
        float q = acc[p][0]*acc[p][0] + acc[p][1]*acc[p][1] + acc[p][2]*acc[p][2];
        #pragma unroll
        for (int off = 32; off > 0; off >>= 1) {
            s += __shfl_xor(s, off, 64);
            q += __shfl_xor(q, off, 64);
        }
        const float mu  = s * (1.f / CC);
        const float var = q * (1.f / CC) - mu * mu;
        const float rs  = rsqrtf(var + 1e-5f);
        float x2v[3];
        #pragma unroll
        for (int j = 0; j < 3; j++) {
            const int c = cslot + 64 * j;
            x2v[j] = x[row * CC + c] + (acc[p][j] - mu) * rs * w1[j] + b1[j];
        }
        float s2 = x2v[0] + x2v[1] + x2v[2];
        float q2 = x2v[0]*x2v[0] + x2v[1]*x2v[1] + x2v[2]*x2v[2];
        #pragma unroll
        for (int off = 32; off > 0; off >>= 1) {
            s2 += __shfl_xor(s2, off, 64);
            q2 += __shfl_xor(q2, off, 64);
        }
        const float mu2  = s2 * (1.f / CC);
        const float var2 = q2 * (1.f / CC) - mu2 * mu2;
        const float rs2  = rsqrtf(var2 + 1e-5f);
        #pragma unroll
        for (int j = 0; j < 3; j++) {
            const int c = cslot + 64 * j;
            x2out[row * CC + c]  = x2v[j];
            xn2out[row * CC + c] = (x2v[j] - mu2) * rs2 * w2[j] + b2[j];
        }
    }
}

// ------- fused depthwise 3x3 conv (SAME) + LN(1e-6) + exact GELU -------------
__global__ __launch_bounds__(192) void dwconv_ln_gelu_k(
        const float* __restrict__ xn, const float* __restrict__ dww,
        const float* __restrict__ dwb, const float* __restrict__ lnw,
        const float* __restrict__ lnb, float* __restrict__ x1)
{
    const int pix  = blockIdx.x;
    const int c    = threadIdx.x;
    const int bimg = pix / (HH * WW);
    const int hw   = pix - bimg * HH * WW;
    const int h    = hw / WW;
    const int w    = hw - h * WW;

    float s = dwb[c];
    #pragma unroll
    for (int ky = 0; ky < 3; ky++) {
        const int yy = h + ky - 1;
        if (yy < 0 || yy >= HH) continue;
        #pragma unroll
        for (int kx = 0; kx < 3; kx++) {
            const int xx = w + kx - 1;
            if (xx < 0 || xx >= WW) continue;
            s += xn[((size_t)(bimg * HH + yy) * WW + xx) * CC + c] *
                 dww[(ky * 3 + kx) * CC + c];
        }
    }
    float sm = s, sq = s * s;
    #pragma unroll
    for (int off = 32; off > 0; off >>= 1) {
        sm += __shfl_xor(sm, off, 64);
        sq += __shfl_xor(sq, off, 64);
    }
    __shared__ float red[6];
    const int wid = threadIdx.x >> 6;
    if ((threadIdx.x & 63) == 0) { red[wid] = sm; red[3 + wid] = sq; }
    __syncthreads();
    const float S = red[0] + red[1] + red[2];
    const float Q = red[3] + red[4] + red[5];
    const float mu  = S * (1.f / CC);
    const float var = Q * (1.f / CC) - mu * mu;
    const float rs  = rsqrtf(var + 1e-6f);
    const float y = (s - mu) * rs * lnw[c] + lnb[c];
    x1[(size_t)pix * CC + c] = gelu_exact(y);
}

// ---- fused sampling: softmax(mask logits) + bilinear gather + cfs blend -----
__global__ __launch_bounds__(192) void sample_k(const float* __restrict__ xp,
        const float* __restrict__ x1g, const float* __restrict__ off,
        const float* __restrict__ mlog, const float* __restrict__ cfsw,
        const float* __restrict__ cfsb, float* __restrict__ outb)
{
    __shared__ float x1s[CC];
    __shared__ float offs[CC];
    __shared__ float mls[96];

    const int pix = blockIdx.x;
    const int t   = threadIdx.x;
    const int bimg = pix / (HH * WW);
    const int hw   = pix - bimg * HH * WW;
    const int h    = hw / WW;
    const int w    = hw - h * WW;

    x1s[t]  = x1g[(size_t)pix * CC + t];
    offs[t] = off[(size_t)pix * CC + t];
    if (t < 96) mls[t] = mlog[(size_t)pix * 96 + t];
    __syncthreads();

    const int g = t >> 4;
    const int c = t & 15;

    float lg[8];
    float mx = -1e30f;
    #pragma unroll
    for (int k = 0; k < 8; k++) { lg[k] = mls[g * 8 + k]; mx = fmaxf(mx, lg[k]); }
    float se = 0.f;
    #pragma unroll
    for (int k = 0; k < 8; k++) { lg[k] = expf(lg[k] - mx); se += lg[k]; }
    const float inv = 1.f / se;

    const int GX[8] = {-1, -1, -1, 0, 0, 1, 1, 1};
    const int GY[8] = {-1, 0, 1, -1, 1, -1, 0, 1};
    const size_t imgbase = (size_t)bimg * HH * WW * CC;

    float acc = 0.f;
    #pragma unroll
    for (int k = 0; k < 8; k++) {
        const float px = (float)w + (float)GX[k] + offs[g * 16 + 2 * k];
        const float py = (float)h + (float)GY[k] + offs[g * 16 + 2 * k + 1];
        const float fx = floorf(px), fy = floorf(py);
        const float wx = px - fx,  wy = py - fy;
        const int x0 = (int)fx, y0 = (int)fy;
        float v00 = 0.f, v01 = 0.f, v10 = 0.f, v11 = 0.f;
        if (y0 >= 0 && y0 < HH) {
            if (x0 >= 0 && x0 < WW)         v00 = xp[imgbase + (size_t)(y0 * WW + x0) * CC + t];
            if (x0 + 1 >= 0 && x0 + 1 < WW) v01 = xp[imgbase + (size_t)(y0 * WW + x0 + 1) * CC + t];
        }
        if (y0 + 1 >= 0 && y0 + 1 < HH) {
            if (x0 >= 0 && x0 < WW)         v10 = xp[imgbase + (size_t)((y0 + 1) * WW + x0) * CC + t];
            if (x0 + 1 >= 0 && x0 + 1 < WW) v11 = xp[imgbase + (size_t)((y0 + 1) * WW + x0 + 1) * CC + t];
        }
        const float bil = (1.f - wy) * ((1.f - wx) * v00 + wx * v01)
                        +         wy * ((1.f - wx) * v10 + wx * v11);
        acc += (lg[k] * inv) * bil;
    }

    float part = 0.f;
    #pragma unroll
    for (int j = 0; j < 12; j++)
        part += x1s[c + 16 * j] * cfsw[(size_t)g * CC + c + 16 * j];
    #pragma unroll
    for (int o = 1; o < 16; o <<= 1) part += __shfl_xor(part, o, 64);
    const float cf = 1.f / (1.f + expf(-(part + cfsb[g])));

    const float xpc = xp[(size_t)pix * CC + t];
    outb[(size_t)pix * CC + t] = acc * (1.f - cf) + xpc * cf;
}

// ---- weight prep: fc1wT[n][k] = bf16(fc1w[k][n]), fc2wT[n][k] = bf16(fc2w[k][n])
__global__ __launch_bounds__(256) void prep_w_k(const float* __restrict__ fc1w,
        const float* __restrict__ fc2w, bf16* __restrict__ fc1wT,
        bf16* __restrict__ fc2wT)
{
    const int i = blockIdx.x * 256 + threadIdx.x;
    if (i < 768 * 192) {
        const int n1 = i / 192, k1 = i - n1 * 192;
        fc1wT[i] = __float2bfloat16(fc1w[(size_t)k1 * 768 + n1]);
        const int n2 = i / 768, k2 = i - n2 * 768;
        fc2wT[i] = __float2bfloat16(fc2w[(size_t)k2 * 192 + n2]);
    }
}

// ---- MFMA MLP: out = x2 + LN(gelu(xn2@fc1+b1)@fc2+b2, rpn2) -----------------
// 64 px/block, 4 waves; wave w owns rows 16w..16w+15 end-to-end (no barriers in
// the K-loop: h1 slice is produced and consumed by the same wave).
// Fragment maps (HW-verified, learn_hip m89/m120): A[m=lane&15][k=quad*8+j],
// B[k=quad*8+j][n=lane&15], D[row=quad*4+reg][col=lane&15].
#define XS_STR 200   // 192 + 8 pad: row stride 400B -> 2-way bank alias (free)
#define H1_STR 72    // 64 + 8 pad:  row stride 144B -> 2-way bank alias (free)
__global__ __launch_bounds__(256) void mlp_mfma_k(const float* __restrict__ xn2,
        const bf16* __restrict__ fc1wT, const float* __restrict__ fc1b,
        const bf16* __restrict__ fc2wT, const float* __restrict__ fc2b,
        const float* __restrict__ x2, const float* __restrict__ r2w,
        const float* __restrict__ r2b, float* __restrict__ out)
{
    __shared__ __align__(16) bf16 xs[64 * XS_STR];   // 25.6 KB
    __shared__ __align__(16) bf16 h1[64 * H1_STR];   //  9.2 KB

    const int tid = threadIdx.x;
    const int w   = tid >> 6;
    const int l   = tid & 63;
    const int n15 = l & 15;
    const int q   = l >> 4;
    const int p0  = blockIdx.x * 64;

    for (int i = tid; i < 64 * 192; i += 256) {
        const int px = i / 192, k = i - px * 192;
        xs[px * XS_STR + k] = __float2bfloat16(xn2[(size_t)(p0 + px) * 192 + k]);
    }
    __syncthreads();

    // A-fragments for this wave's 16 rows (K=192 -> 6 chunks), reused all kc
    short8 aF[6];
    #pragma unroll
    for (int c = 0; c < 6; c++)
        aF[c] = *(const short8*)&xs[(16 * w + n15) * XS_STR + c * 32 + q * 8];

    float4v acc2[12];
    #pragma unroll
    for (int t = 0; t < 12; t++) acc2[t] = (float4v){0.f, 0.f, 0.f, 0.f};

    for (int kc = 0; kc < 768; kc += 64) {
        // fc1: h1 cols kc..kc+64 for this wave's 16 rows
        #pragma unroll
        for (int t1 = 0; t1 < 4; t1++) {
            const int n0 = kc + 16 * t1;
            float4v a1 = (float4v){0.f, 0.f, 0.f, 0.f};
            #pragma unroll
            for (int c = 0; c < 6; c++) {
                const short8 bF = *(const short8*)&fc1wT[(size_t)(n0 + n15) * 192 + c * 32 + q * 8];
                a1 = __builtin_amdgcn_mfma_f32_16x16x32_bf16(aF[c], bF, a1, 0, 0, 0);
            }
            const float bb = fc1b[n0 + n15];
            #pragma unroll
            for (int r = 0; r < 4; r++) {
                const float hv = gelu_exact(a1[r] + bb);
                h1[(16 * w + 4 * q + r) * H1_STR + 16 * t1 + n15] = __float2bfloat16(hv);
            }
        }
        // fc2 partial accumulate over k in [kc, kc+64)  (same-wave h1 reuse)
        #pragma unroll
        for (int c2 = 0; c2 < 2; c2++) {
            const short8 a2 = *(const short8*)&h1[(16 * w + n15) * H1_STR + c2 * 32 + q * 8];
            #pragma unroll
            for (int t = 0; t < 12; t++) {
                const short8 bF = *(const short8*)&fc2wT[(size_t)(16 * t + n15) * 768 + kc + c2 * 32 + q * 8];
                acc2[t] = __builtin_amdgcn_mfma_f32_16x16x32_bf16(a2, bF, acc2[t], 0, 0, 0);
            }
        }
    }

    // epilogue: + fc2 bias, LN(rpn2) per row, + x2 residual
    #pragma unroll
    for (int t = 0; t < 12; t++) {
        const float bb = fc2b[16 * t + n15];
        #pragma unroll
        for (int r = 0; r < 4; r++) acc2[t][r] += bb;
    }
    #pragma unroll
    for (int r = 0; r < 4; r++) {
        float s = 0.f, qs = 0.f;
        #pragma unroll
        for (int t = 0; t < 12; t++) { s += acc2[t][r]; qs += acc2[t][r] * acc2[t][r]; }
        #pragma unroll
        for (int o = 1; o < 16; o <<= 1) {
            s  += __shfl_xor(s, o, 64);
            qs += __shfl_xor(qs, o, 64);
        }
        const float mu  = s * (1.f / CC);
        const float var = qs * (1.f / CC) - mu * mu;
        const float rs  = rsqrtf(var + 1e-5f);
        const size_t row = p0 + 16 * w + 4 * q + r;
        #pragma unroll
        for (int t = 0; t < 12; t++) {
            const int col = 16 * t + n15;
            out[row * CC + col] = x2[row * CC + col]
                                + (acc2[t][r] - mu) * rs * r2w[col] + r2b[col];
        }
    }
}

extern "C" void kernel_launch(void* const* d_in, const int* in_sizes, int n_in,
                              void* d_out, int out_size, void* d_ws, size_t ws_size,
                              hipStream_t stream) {
    const float* x      = (const float*)d_in[0];
    const float* n1w    = (const float*)d_in[1];
    const float* n1b    = (const float*)d_in[2];
    const float* n2w    = (const float*)d_in[3];
    const float* n2b    = (const float*)d_in[4];
    const float* rpn1w  = (const float*)d_in[5];
    const float* rpn1b  = (const float*)d_in[6];
    const float* rpn2w  = (const float*)d_in[7];
    const float* rpn2b  = (const float*)d_in[8];
    const float* inpw   = (const float*)d_in[9];
    const float* inpb   = (const float*)d_in[10];
    const float* dww    = (const float*)d_in[11];
    const float* dwb    = (const float*)d_in[12];
    const float* dwlnw  = (const float*)d_in[13];
    const float* dwlnb  = (const float*)d_in[14];
    const float* offw   = (const float*)d_in[15];
    const float* offb   = (const float*)d_in[16];
    const float* maskw  = (const float*)d_in[17];
    const float* maskb  = (const float*)d_in[18];
    const float* cfsw   = (const float*)d_in[19];
    const float* cfsb   = (const float*)d_in[20];
    const float* outpw  = (const float*)d_in[21];
    const float* outpb  = (const float*)d_in[22];
    const float* fc1w   = (const float*)d_in[23];
    const float* fc1b   = (const float*)d_in[24];
    const float* fc2w   = (const float*)d_in[25];
    const float* fc2b   = (const float*)d_in[26];

    const int N = NPIX;                       // 12544
    const size_t NP = (size_t)N * CC;
    float* F0 = (float*)d_ws;                 // xn -> blended
    float* F1 = F0 + NP;                      // xp -> x2
    float* F2 = F1 + NP;                      // off
    float* F3 = F2 + NP;                      // x1 -> xn2
    float* Fm = F3 + NP;                      // mask logits N*96
    bf16* fc1wT = (bf16*)(Fm + (size_t)N * 96);      // 768*192 bf16 (16B-aligned)
    bf16* fc2wT = fc1wT + 768 * 192;                 // 192*768 bf16

    const int lnG = N / 4;     // 3136
    const int gmG = N / 32;    // 392

    // 0. weight prep for MFMA MLP (bf16, transposed to [N][K])
    prep_w_k<<<(768 * 192 + 255) / 256, 256, 0, stream>>>(fc1w, fc2w, fc1wT, fc2wT);
    // 1. xn = LN(x, norm1)                         -> F0
    ln4_k<<<lnG, 256, 0, stream>>>(x, n1w, n1b, F0, 1e-5f);
    // 2. xp = xn @ in_proj + b                     -> F1
    gemm_k<<<gmG, 256, 0, stream>>>(F0, inpw, inpb, F1, CC);
    // 3. x1 = gelu(LN(dwconv(xn), 1e-6))           -> F3
    dwconv_ln_gelu_k<<<N, 192, 0, stream>>>(F0, dww, dwb, dwlnw, dwlnb, F3);
    // 4. off = x1 @ off_w + b                      -> F2
    gemm_k<<<gmG, 256, 0, stream>>>(F3, offw, offb, F2, CC);
    // 5. mask logits = x1 @ mask_w + b             -> Fm
    gemm_k<<<gmG, 256, 0, stream>>>(F3, maskw, maskb, Fm, 96);
    // 6. blended = sample(xp, x1, off, mlog)       -> F0
    sample_k<<<N, 192, 0, stream>>>(F1, F3, F2, Fm, cfsw, cfsb, F0);
    // 7. x2 = x + LN(blended@out_proj+b, rpn1); xn2 = LN(x2, norm2)
    gemm_ln2_k<<<gmG, 256, 0, stream>>>(F0, outpw, outpb, x, rpn1w, rpn1b,
                                        n2w, n2b, F1, F3);
    // 8. out = x2 + LN(gelu(xn2@fc1)@fc2, rpn2)    -> d_out  (MFMA)
    mlp_mfma_k<<<N / 64, 256, 0, stream>>>(F3, fc1wT, fc1b, fc2wT, fc2b,
                                           F1, rpn2w, rpn2b, (float*)d_out);
}

// Round 12
// 327.272 us; speedup vs baseline: 1.5625x; 1.3111x over previous
//
#include <hip/hip_runtime.h>
#include <hip/hip_bf16.h>
#include <math.h>

// InternImage DCNv3 block forward — round 12: ALL GEMMs on MFMA.
// r11: mlp MFMA correct but 84us at 8% occupancy (196 blocks < 256 CUs,
// latency-bound).  r12: 16px/block everywhere (784 blocks), waves split N,
// off+mask GEMMs fused (share A-tile), out_proj keeps fused double-LN via
// cross-wave LDS partials.  bf16 inputs / fp32 accum+epilogue.
// ws: F0..F3 (N*192 fp32) | Fm (N*96 fp32) | bf16 wT region (848KB).

#define BATCH 4
#define HH 56
#define WW 56
#define CC 192
#define NPIX (BATCH * HH * WW)   // 12544
#define XS_STR 200               // 192+8: 400B row stride, 16B aligned
#define H1S 776                  // 768+8: 1552B row stride, 16B aligned

typedef __hip_bfloat16 bf16;
typedef __attribute__((ext_vector_type(8))) short short8;
typedef __attribute__((ext_vector_type(4))) float float4v;

__device__ __forceinline__ float gelu_exact(float x) {
    return 0.5f * x * (1.f + erff(x * 0.70710678118654752f));
}
__device__ __forceinline__ bf16 f2b(float f) { return __float2bfloat16(f); }

// ---------------- LN over C=192, one wave per pixel, 4 px/block --------------
__global__ __launch_bounds__(256) void ln4_k(const float* __restrict__ X,
        const float* __restrict__ w, const float* __restrict__ b,
        float* __restrict__ out, float eps)
{
    const int pix  = blockIdx.x * 4 + (threadIdx.x >> 6);
    const int lane = threadIdx.x & 63;
    const size_t base = (size_t)pix * CC;
    float v[3];
    #pragma unroll
    for (int i = 0; i < 3; i++) v[i] = X[base + lane + 64 * i];
    float s = v[0] + v[1] + v[2];
    float q = v[0]*v[0] + v[1]*v[1] + v[2]*v[2];
    #pragma unroll
    for (int off = 32; off > 0; off >>= 1) {
        s += __shfl_xor(s, off, 64);
        q += __shfl_xor(q, off, 64);
    }
    const float mu  = s * (1.f / CC);
    const float var = q * (1.f / CC) - mu * mu;
    const float rs  = rsqrtf(var + eps);
    #pragma unroll
    for (int i = 0; i < 3; i++) {
        const int c = lane + 64 * i;
        out[base + c] = (v[i] - mu) * rs * w[c] + b[c];
    }
}

// ------- fused depthwise 3x3 conv (SAME) + LN(1e-6) + exact GELU -------------
__global__ __launch_bounds__(192) void dwconv_ln_gelu_k(
        const float* __restrict__ xn, const float* __restrict__ dww,
        const float* __restrict__ dwb, const float* __restrict__ lnw,
        const float* __restrict__ lnb, float* __restrict__ x1)
{
    const int pix  = blockIdx.x;
    const int c    = threadIdx.x;
    const int bimg = pix / (HH * WW);
    const int hw   = pix - bimg * HH * WW;
    const int h    = hw / WW;
    const int w    = hw - h * WW;

    float s = dwb[c];
    #pragma unroll
    for (int ky = 0; ky < 3; ky++) {
        const int yy = h + ky - 1;
        if (yy < 0 || yy >= HH) continue;
        #pragma unroll
        for (int kx = 0; kx < 3; kx++) {
            const int xx = w + kx - 1;
            if (xx < 0 || xx >= WW) continue;
            s += xn[((size_t)(bimg * HH + yy) * WW + xx) * CC + c] *
                 dww[(ky * 3 + kx) * CC + c];
        }
    }
    float sm = s, sq = s * s;
    #pragma unroll
    for (int off = 32; off > 0; off >>= 1) {
        sm += __shfl_xor(sm, off, 64);
        sq += __shfl_xor(sq, off, 64);
    }
    __shared__ float red[6];
    const int wid = threadIdx.x >> 6;
    if ((threadIdx.x & 63) == 0) { red[wid] = sm; red[3 + wid] = sq; }
    __syncthreads();
    const float S = red[0] + red[1] + red[2];
    const float Q = red[3] + red[4] + red[5];
    const float mu  = S * (1.f / CC);
    const float var = Q * (1.f / CC) - mu * mu;
    const float rs  = rsqrtf(var + 1e-6f);
    const float y = (s - mu) * rs * lnw[c] + lnb[c];
    x1[(size_t)pix * CC + c] = gelu_exact(y);
}

// ---- fused sampling: softmax(mask logits) + bilinear gather + cfs blend -----
__global__ __launch_bounds__(192) void sample_k(const float* __restrict__ xp,
        const float* __restrict__ x1g, const float* __restrict__ off,
        const float* __restrict__ mlog, const float* __restrict__ cfsw,
        const float* __restrict__ cfsb, float* __restrict__ outb)
{
    __shared__ float x1s[CC];
    __shared__ float offs[CC];
    __shared__ float mls[96];

    const int pix = blockIdx.x;
    const int t   = threadIdx.x;
    const int bimg = pix / (HH * WW);
    const int hw   = pix - bimg * HH * WW;
    const int h    = hw / WW;
    const int w    = hw - h * WW;

    x1s[t]  = x1g[(size_t)pix * CC + t];
    offs[t] = off[(size_t)pix * CC + t];
    if (t < 96) mls[t] = mlog[(size_t)pix * 96 + t];
    __syncthreads();

    const int g = t >> 4;
    const int c = t & 15;

    float lg[8];
    float mx = -1e30f;
    #pragma unroll
    for (int k = 0; k < 8; k++) { lg[k] = mls[g * 8 + k]; mx = fmaxf(mx, lg[k]); }
    float se = 0.f;
    #pragma unroll
    for (int k = 0; k < 8; k++) { lg[k] = expf(lg[k] - mx); se += lg[k]; }
    const float inv = 1.f / se;

    const int GX[8] = {-1, -1, -1, 0, 0, 1, 1, 1};
    const int GY[8] = {-1, 0, 1, -1, 1, -1, 0, 1};
    const size_t imgbase = (size_t)bimg * HH * WW * CC;

    float acc = 0.f;
    #pragma unroll
    for (int k = 0; k < 8; k++) {
        const float px = (float)w + (float)GX[k] + offs[g * 16 + 2 * k];
        const float py = (float)h + (float)GY[k] + offs[g * 16 + 2 * k + 1];
        const float fx = floorf(px), fy = floorf(py);
        const float wx = px - fx,  wy = py - fy;
        const int x0 = (int)fx, y0 = (int)fy;
        float v00 = 0.f, v01 = 0.f, v10 = 0.f, v11 = 0.f;
        if (y0 >= 0 && y0 < HH) {
            if (x0 >= 0 && x0 < WW)         v00 = xp[imgbase + (size_t)(y0 * WW + x0) * CC + t];
            if (x0 + 1 >= 0 && x0 + 1 < WW) v01 = xp[imgbase + (size_t)(y0 * WW + x0 + 1) * CC + t];
        }
        if (y0 + 1 >= 0 && y0 + 1 < HH) {
            if (x0 >= 0 && x0 < WW)         v10 = xp[imgbase + (size_t)((y0 + 1) * WW + x0) * CC + t];
            if (x0 + 1 >= 0 && x0 + 1 < WW) v11 = xp[imgbase + (size_t)((y0 + 1) * WW + x0 + 1) * CC + t];
        }
        const float bil = (1.f - wy) * ((1.f - wx) * v00 + wx * v01)
                        +         wy * ((1.f - wx) * v10 + wx * v11);
        acc += (lg[k] * inv) * bil;
    }

    float part = 0.f;
    #pragma unroll
    for (int j = 0; j < 12; j++)
        part += x1s[c + 16 * j] * cfsw[(size_t)g * CC + c + 16 * j];
    #pragma unroll
    for (int o = 1; o < 16; o <<= 1) part += __shfl_xor(part, o, 64);
    const float cf = 1.f / (1.f + expf(-(part + cfsb[g])));

    const float xpc = xp[(size_t)pix * CC + t];
    outb[(size_t)pix * CC + t] = acc * (1.f - cf) + xpc * cf;
}

// ---- weight prep: transpose all GEMM weights to bf16 [N][K] -----------------
// layout in wsB: inpwT(36864) | offmaskT(55296) | outpwT(36864) |
//                fc1wT(147456) | fc2wT(147456)
__global__ __launch_bounds__(256) void prep_w_k(const float* __restrict__ inpw,
        const float* __restrict__ offw, const float* __restrict__ maskw,
        const float* __restrict__ outpw, const float* __restrict__ fc1w,
        const float* __restrict__ fc2w, bf16* __restrict__ wsB)
{
    const int i = blockIdx.x * 256 + threadIdx.x;
    bf16* inpwT   = wsB;
    bf16* offmaskT= wsB + 36864;
    bf16* outpwT  = wsB + 92160;
    bf16* fc1wT   = wsB + 129024;
    bf16* fc2wT   = wsB + 276480;
    if (i < 36864) {
        const int n = i / 192, k = i - n * 192;
        inpwT[i]  = f2b(inpw[(size_t)k * 192 + n]);
        outpwT[i] = f2b(outpw[(size_t)k * 192 + n]);
    }
    if (i < 55296) {
        const int n = i / 192, k = i - n * 192;
        offmaskT[i] = (n < 192) ? f2b(offw[(size_t)k * 192 + n])
                                : f2b(maskw[(size_t)k * 96 + (n - 192)]);
    }
    if (i < 147456) {
        const int n1 = i / 192, k1 = i - n1 * 192;
        fc1wT[i] = f2b(fc1w[(size_t)k1 * 768 + n1]);
        const int n2 = i / 768, k2 = i - n2 * 768;
        fc2wT[i] = f2b(fc2w[(size_t)k2 * 192 + n2]);
    }
}

// ---- generic MFMA GEMM: out[16px][192] = A @ wT^T + bias, 16px/block --------
// 4 waves x 3 N-tiles.  A staged bf16 in LDS.  Fragment maps verified r11.
__global__ __launch_bounds__(256) void gemm16_k(const float* __restrict__ A,
        const bf16* __restrict__ wT, const float* __restrict__ bias,
        float* __restrict__ out)
{
    __shared__ __align__(16) bf16 xs[16 * XS_STR];
    const int tid = threadIdx.x;
    const int w   = tid >> 6;
    const int l   = tid & 63;
    const int n15 = l & 15;
    const int q   = l >> 4;
    const int p0  = blockIdx.x * 16;

    for (int i = tid; i < 16 * 192; i += 256) {
        const int px = i / 192, k = i - px * 192;
        xs[px * XS_STR + k] = f2b(A[(size_t)(p0 + px) * 192 + k]);
    }
    __syncthreads();

    short8 aF[6];
    #pragma unroll
    for (int c = 0; c < 6; c++)
        aF[c] = *(const short8*)&xs[n15 * XS_STR + c * 32 + q * 8];

    #pragma unroll
    for (int t = 0; t < 3; t++) {
        const int n0 = 48 * w + 16 * t;
        float4v acc = (float4v){0.f, 0.f, 0.f, 0.f};
        #pragma unroll
        for (int c = 0; c < 6; c++) {
            const short8 bF = *(const short8*)&wT[(size_t)(n0 + n15) * 192 + c * 32 + q * 8];
            acc = __builtin_amdgcn_mfma_f32_16x16x32_bf16(aF[c], bF, acc, 0, 0, 0);
        }
        const float bb = bias[n0 + n15];
        #pragma unroll
        for (int r = 0; r < 4; r++)
            out[(size_t)(p0 + 4 * q + r) * 192 + n0 + n15] = acc[r] + bb;
    }
}

// ---- off+mask fused MFMA GEMM: A=x1, wT 288 rows (192 off + 96 mask) --------
__global__ __launch_bounds__(256) void gemm_offmask_k(const float* __restrict__ A,
        const bf16* __restrict__ wT, const float* __restrict__ offb,
        const float* __restrict__ maskb, float* __restrict__ offo,
        float* __restrict__ masko)
{
    __shared__ __align__(16) bf16 xs[16 * XS_STR];
    const int tid = threadIdx.x;
    const int w   = tid >> 6;
    const int l   = tid & 63;
    const int n15 = l & 15;
    const int q   = l >> 4;
    const int p0  = blockIdx.x * 16;

    for (int i = tid; i < 16 * 192; i += 256) {
        const int px = i / 192, k = i - px * 192;
        xs[px * XS_STR + k] = f2b(A[(size_t)(p0 + px) * 192 + k]);
    }
    __syncthreads();

    short8 aF[6];
    #pragma unroll
    for (int c = 0; c < 6; c++)
        aF[c] = *(const short8*)&xs[n15 * XS_STR + c * 32 + q * 8];

    for (int t = w; t < 18; t += 4) {
        const int n0 = 16 * t;
        float4v acc = (float4v){0.f, 0.f, 0.f, 0.f};
        #pragma unroll
        for (int c = 0; c < 6; c++) {
            const short8 bF = *(const short8*)&wT[(size_t)(n0 + n15) * 192 + c * 32 + q * 8];
            acc = __builtin_amdgcn_mfma_f32_16x16x32_bf16(aF[c], bF, acc, 0, 0, 0);
        }
        if (t < 12) {
            const float bb = offb[n0 + n15];
            #pragma unroll
            for (int r = 0; r < 4; r++)
                offo[(size_t)(p0 + 4 * q + r) * 192 + n0 + n15] = acc[r] + bb;
        } else {
            const int m0 = n0 - 192;
            const float bb = maskb[m0 + n15];
            #pragma unroll
            for (int r = 0; r < 4; r++)
                masko[(size_t)(p0 + 4 * q + r) * 96 + m0 + n15] = acc[r] + bb;
        }
    }
}

// ---- out_proj MFMA GEMM + x2 = x + LN(d,rpn1) + xn2 = LN(x2,norm2) ----------
// Cross-wave LN via LDS partials (each wave owns 48 of the 192 cols).
__global__ __launch_bounds__(256) void gemm_ln2_mfma_k(const float* __restrict__ A,
        const bf16* __restrict__ wT, const float* __restrict__ bias,
        const float* __restrict__ x,
        const float* __restrict__ r1w, const float* __restrict__ r1b,
        const float* __restrict__ n2w, const float* __restrict__ n2b,
        float* __restrict__ x2out, float* __restrict__ xn2out)
{
    __shared__ __align__(16) bf16 xs[16 * XS_STR];
    __shared__ float ps[4][16], pq[4][16], ps2[4][16], pq2[4][16];
    const int tid = threadIdx.x;
    const int w   = tid >> 6;
    const int l   = tid & 63;
    const int n15 = l & 15;
    const int q   = l >> 4;
    const int p0  = blockIdx.x * 16;

    for (int i = tid; i < 16 * 192; i += 256) {
        const int px = i / 192, k = i - px * 192;
        xs[px * XS_STR + k] = f2b(A[(size_t)(p0 + px) * 192 + k]);
    }
    __syncthreads();

    short8 aF[6];
    #pragma unroll
    for (int c = 0; c < 6; c++)
        aF[c] = *(const short8*)&xs[n15 * XS_STR + c * 32 + q * 8];

    float4v acc[3];
    #pragma unroll
    for (int t = 0; t < 3; t++) {
        const int n0 = 48 * w + 16 * t;
        acc[t] = (float4v){0.f, 0.f, 0.f, 0.f};
        #pragma unroll
        for (int c = 0; c < 6; c++) {
            const short8 bF = *(const short8*)&wT[(size_t)(n0 + n15) * 192 + c * 32 + q * 8];
            acc[t] = __builtin_amdgcn_mfma_f32_16x16x32_bf16(aF[c], bF, acc[t], 0, 0, 0);
        }
        const float bb = bias[n0 + n15];
        #pragma unroll
        for (int r = 0; r < 4; r++) acc[t][r] += bb;
    }

    // LN1 partials (48 cols per wave)
    #pragma unroll
    for (int r = 0; r < 4; r++) {
        float sp = acc[0][r] + acc[1][r] + acc[2][r];
        float qp = acc[0][r]*acc[0][r] + acc[1][r]*acc[1][r] + acc[2][r]*acc[2][r];
        #pragma unroll
        for (int o = 1; o < 16; o <<= 1) {
            sp += __shfl_xor(sp, o, 64);
            qp += __shfl_xor(qp, o, 64);
        }
        if (n15 == 0) { ps[w][4 * q + r] = sp; pq[w][4 * q + r] = qp; }
    }
    __syncthreads();

    float x2v[3][4];
    #pragma unroll
    for (int r = 0; r < 4; r++) {
        const int row = 4 * q + r;
        const float s  = ps[0][row] + ps[1][row] + ps[2][row] + ps[3][row];
        const float qq = pq[0][row] + pq[1][row] + pq[2][row] + pq[3][row];
        const float mu  = s * (1.f / CC);
        const float var = qq * (1.f / CC) - mu * mu;
        const float rs  = rsqrtf(var + 1e-5f);
        const size_t grow = p0 + row;
        #pragma unroll
        for (int t = 0; t < 3; t++) {
            const int col = 48 * w + 16 * t + n15;
            x2v[t][r] = x[grow * CC + col] + (acc[t][r] - mu) * rs * r1w[col] + r1b[col];
        }
    }

    // LN2 partials
    #pragma unroll
    for (int r = 0; r < 4; r++) {
        float sp = x2v[0][r] + x2v[1][r] + x2v[2][r];
        float qp = x2v[0][r]*x2v[0][r] + x2v[1][r]*x2v[1][r] + x2v[2][r]*x2v[2][r];
        #pragma unroll
        for (int o = 1; o < 16; o <<= 1) {
            sp += __shfl_xor(sp, o, 64);
            qp += __shfl_xor(qp, o, 64);
        }
        if (n15 == 0) { ps2[w][4 * q + r] = sp; pq2[w][4 * q + r] = qp; }
    }
    __syncthreads();

    #pragma unroll
    for (int r = 0; r < 4; r++) {
        const int row = 4 * q + r;
        const float s  = ps2[0][row] + ps2[1][row] + ps2[2][row] + ps2[3][row];
        const float qq = pq2[0][row] + pq2[1][row] + pq2[2][row] + pq2[3][row];
        const float mu  = s * (1.f / CC);
        const float var = qq * (1.f / CC) - mu * mu;
        const float rs  = rsqrtf(var + 1e-5f);
        const size_t grow = p0 + row;
        #pragma unroll
        for (int t = 0; t < 3; t++) {
            const int col = 48 * w + 16 * t + n15;
            x2out[grow * CC + col]  = x2v[t][r];
            xn2out[grow * CC + col] = (x2v[t][r] - mu) * rs * n2w[col] + n2b[col];
        }
    }
}

// ---- MFMA MLP: out = x2 + LN(gelu(xn2@fc1+b1)@fc2+b2, rpn2), 16px/block -----
// fc1: wave w -> cols [192w,192w+192); fc2: wave w -> cols [48w,48w+48).
__global__ __launch_bounds__(256) void mlp_mfma16_k(const float* __restrict__ xn2,
        const bf16* __restrict__ fc1wT, const float* __restrict__ fc1b,
        const bf16* __restrict__ fc2wT, const float* __restrict__ fc2b,
        const float* __restrict__ x2, const float* __restrict__ r2w,
        const float* __restrict__ r2b, float* __restrict__ out)
{
    __shared__ __align__(16) bf16 xs[16 * XS_STR];   // 6.4 KB
    __shared__ __align__(16) bf16 h1[16 * H1S];      // 24.8 KB
    __shared__ float ps[4][16], pq[4][16];

    const int tid = threadIdx.x;
    const int w   = tid >> 6;
    const int l   = tid & 63;
    const int n15 = l & 15;
    const int q   = l >> 4;
    const int p0  = blockIdx.x * 16;

    for (int i = tid; i < 16 * 192; i += 256) {
        const int px = i / 192, k = i - px * 192;
        xs[px * XS_STR + k] = f2b(xn2[(size_t)(p0 + px) * 192 + k]);
    }
    __syncthreads();

    short8 aF[6];
    #pragma unroll
    for (int c = 0; c < 6; c++)
        aF[c] = *(const short8*)&xs[n15 * XS_STR + c * 32 + q * 8];

    // fc1 + GELU -> h1 (wave w covers cols 192w..192w+191)
    #pragma unroll
    for (int t1 = 0; t1 < 12; t1++) {
        const int n0 = 192 * w + 16 * t1;
        float4v a1 = (float4v){0.f, 0.f, 0.f, 0.f};
        #pragma unroll
        for (int c = 0; c < 6; c++) {
            const short8 bF = *(const short8*)&fc1wT[(size_t)(n0 + n15) * 192 + c * 32 + q * 8];
            a1 = __builtin_amdgcn_mfma_f32_16x16x32_bf16(aF[c], bF, a1, 0, 0, 0);
        }
        const float bb = fc1b[n0 + n15];
        #pragma unroll
        for (int r = 0; r < 4; r++)
            h1[(4 * q + r) * H1S + n0 + n15] = f2b(gelu_exact(a1[r] + bb));
    }
    __syncthreads();

    // fc2: wave w covers out cols 48w..48w+47, K = 768
    float4v acc2[3];
    #pragma unroll
    for (int t = 0; t < 3; t++) acc2[t] = (float4v){0.f, 0.f, 0.f, 0.f};
    for (int kc = 0; kc < 24; kc++) {
        const short8 a2 = *(const short8*)&h1[n15 * H1S + kc * 32 + q * 8];
        #pragma unroll
        for (int t = 0; t < 3; t++) {
            const int n0 = 48 * w + 16 * t;
            const short8 bF = *(const short8*)&fc2wT[(size_t)(n0 + n15) * 768 + kc * 32 + q * 8];
            acc2[t] = __builtin_amdgcn_mfma_f32_16x16x32_bf16(a2, bF, acc2[t], 0, 0, 0);
        }
    }
    #pragma unroll
    for (int t = 0; t < 3; t++) {
        const float bb = fc2b[48 * w + 16 * t + n15];
        #pragma unroll
        for (int r = 0; r < 4; r++) acc2[t][r] += bb;
    }

    // LN(rpn2) partials across waves
    #pragma unroll
    for (int r = 0; r < 4; r++) {
        float sp = acc2[0][r] + acc2[1][r] + acc2[2][r];
        float qp = acc2[0][r]*acc2[0][r] + acc2[1][r]*acc2[1][r] + acc2[2][r]*acc2[2][r];
        #pragma unroll
        for (int o = 1; o < 16; o <<= 1) {
            sp += __shfl_xor(sp, o, 64);
            qp += __shfl_xor(qp, o, 64);
        }
        if (n15 == 0) { ps[w][4 * q + r] = sp; pq[w][4 * q + r] = qp; }
    }
    __syncthreads();

    #pragma unroll
    for (int r = 0; r < 4; r++) {
        const int row = 4 * q + r;
        const float s  = ps[0][row] + ps[1][row] + ps[2][row] + ps[3][row];
        const float qq = pq[0][row] + pq[1][row] + pq[2][row] + pq[3][row];
        const float mu  = s * (1.f / CC);
        const float var = qq * (1.f / CC) - mu * mu;
        const float rs  = rsqrtf(var + 1e-5f);
        const size_t grow = p0 + row;
        #pragma unroll
        for (int t = 0; t < 3; t++) {
            const int col = 48 * w + 16 * t + n15;
            out[grow * CC + col] = x2[grow * CC + col]
                                 + (acc2[t][r] - mu) * rs * r2w[col] + r2b[col];
        }
    }
}

extern "C" void kernel_launch(void* const* d_in, const int* in_sizes, int n_in,
                              void* d_out, int out_size, void* d_ws, size_t ws_size,
                              hipStream_t stream) {
    const float* x      = (const float*)d_in[0];
    const float* n1w    = (const float*)d_in[1];
    const float* n1b    = (const float*)d_in[2];
    const float* n2w    = (const float*)d_in[3];
    const float* n2b    = (const float*)d_in[4];
    const float* rpn1w  = (const float*)d_in[5];
    const float* rpn1b  = (const float*)d_in[6];
    const float* rpn2w  = (const float*)d_in[7];
    const float* rpn2b  = (const float*)d_in[8];
    const float* inpw   = (const float*)d_in[9];
    const float* inpb   = (const float*)d_in[10];
    const float* dww    = (const float*)d_in[11];
    const float* dwb    = (const float*)d_in[12];
    const float* dwlnw  = (const float*)d_in[13];
    const float* dwlnb  = (const float*)d_in[14];
    const float* offw   = (const float*)d_in[15];
    const float* offb   = (const float*)d_in[16];
    const float* maskw  = (const float*)d_in[17];
    const float* maskb  = (const float*)d_in[18];
    const float* cfsw   = (const float*)d_in[19];
    const float* cfsb   = (const float*)d_in[20];
    const float* outpw  = (const float*)d_in[21];
    const float* outpb  = (const float*)d_in[22];
    const float* fc1w   = (const float*)d_in[23];
    const float* fc1b   = (const float*)d_in[24];
    const float* fc2w   = (const float*)d_in[25];
    const float* fc2b   = (const float*)d_in[26];

    const int N = NPIX;                       // 12544
    const size_t NP = (size_t)N * CC;
    float* F0 = (float*)d_ws;                 // xn -> blended
    float* F1 = F0 + NP;                      // xp -> x2
    float* F2 = F1 + NP;                      // off
    float* F3 = F2 + NP;                      // x1 -> xn2
    float* Fm = F3 + NP;                      // mask logits N*96
    bf16* wsB = (bf16*)(Fm + (size_t)N * 96); // bf16 transposed weights
    const bf16* inpwT    = wsB;
    const bf16* offmaskT = wsB + 36864;
    const bf16* outpwT   = wsB + 92160;
    const bf16* fc1wT    = wsB + 129024;
    const bf16* fc2wT    = wsB + 276480;

    const int lnG = N / 4;     // 3136
    const int g16 = N / 16;    // 784

    // 0. weight prep (bf16, [N][K])
    prep_w_k<<<576, 256, 0, stream>>>(inpw, offw, maskw, outpw, fc1w, fc2w, wsB);
    // 1. xn = LN(x, norm1)                         -> F0
    ln4_k<<<lnG, 256, 0, stream>>>(x, n1w, n1b, F0, 1e-5f);
    // 2. xp = xn @ in_proj + b                     -> F1
    gemm16_k<<<g16, 256, 0, stream>>>(F0, inpwT, inpb, F1);
    // 3. x1 = gelu(LN(dwconv(xn), 1e-6))           -> F3
    dwconv_ln_gelu_k<<<N, 192, 0, stream>>>(F0, dww, dwb, dwlnw, dwlnb, F3);
    // 4. off -> F2, mask logits -> Fm (fused, shared A-tile)
    gemm_offmask_k<<<g16, 256, 0, stream>>>(F3, offmaskT, offb, maskb, F2, Fm);
    // 5. blended = sample(xp, x1, off, mlog)       -> F0
    sample_k<<<N, 192, 0, stream>>>(F1, F3, F2, Fm, cfsw, cfsb, F0);
    // 6. x2 = x + LN(blended@out_proj+b, rpn1); xn2 = LN(x2, norm2)
    gemm_ln2_mfma_k<<<g16, 256, 0, stream>>>(F0, outpwT, outpb, x, rpn1w, rpn1b,
                                             n2w, n2b, F1, F3);
    // 7. out = x2 + LN(gelu(xn2@fc1)@fc2, rpn2)    -> d_out
    mlp_mfma16_k<<<g16, 256, 0, stream>>>(F3, fc1wT, fc1b, fc2wT, fc2b,
                                          F1, rpn2w, rpn2b, (float*)d_out);
}

// Round 13
// 264.006 us; speedup vs baseline: 1.9369x; 1.2396x over previous
//
#include <hip/hip_runtime.h>
#include <hip/hip_bf16.h>
#include <math.h>

// InternImage DCNv3 block forward — round 13: fragment-packed MFMA weights.
// r12 post-mortem: B-fragment loads were 16-row strided gathers (16x L2
// request amplification) -> VMEM pipe saturated, occupancy gain neutral.
// r13: weights pre-packed in MFMA fragment order; every wave B-load is one
// coalesced 1KB dwordx4.  Kernel structure otherwise identical to r12.
// ws: F0..F3 (N*192 fp32) | Fm (N*96 fp32) | packed bf16 weights (848KB).

#define BATCH 4
#define HH 56
#define WW 56
#define CC 192
#define NPIX (BATCH * HH * WW)   // 12544
#define XS_STR 200               // 192+8: 400B row stride, 16B aligned
#define H1S 776                  // 768+8: 1552B row stride, 16B aligned

typedef __hip_bfloat16 bf16;
typedef __attribute__((ext_vector_type(8))) short short8;
typedef __attribute__((ext_vector_type(4))) float float4v;

__device__ __forceinline__ float gelu_exact(float x) {
    return 0.5f * x * (1.f + erff(x * 0.70710678118654752f));
}
__device__ __forceinline__ bf16 f2b(float f) { return __float2bfloat16(f); }

// ---------------- LN over C=192, one wave per pixel, 4 px/block --------------
__global__ __launch_bounds__(256) void ln4_k(const float* __restrict__ X,
        const float* __restrict__ w, const float* __restrict__ b,
        float* __restrict__ out, float eps)
{
    const int pix  = blockIdx.x * 4 + (threadIdx.x >> 6);
    const int lane = threadIdx.x & 63;
    const size_t base = (size_t)pix * CC;
    float v[3];
    #pragma unroll
    for (int i = 0; i < 3; i++) v[i] = X[base + lane + 64 * i];
    float s = v[0] + v[1] + v[2];
    float q = v[0]*v[0] + v[1]*v[1] + v[2]*v[2];
    #pragma unroll
    for (int off = 32; off > 0; off >>= 1) {
        s += __shfl_xor(s, off, 64);
        q += __shfl_xor(q, off, 64);
    }
    const float mu  = s * (1.f / CC);
    const float var = q * (1.f / CC) - mu * mu;
    const float rs  = rsqrtf(var + eps);
    #pragma unroll
    for (int i = 0; i < 3; i++) {
        const int c = lane + 64 * i;
        out[base + c] = (v[i] - mu) * rs * w[c] + b[c];
    }
}

// ------- fused depthwise 3x3 conv (SAME) + LN(1e-6) + exact GELU -------------
__global__ __launch_bounds__(192) void dwconv_ln_gelu_k(
        const float* __restrict__ xn, const float* __restrict__ dww,
        const float* __restrict__ dwb, const float* __restrict__ lnw,
        const float* __restrict__ lnb, float* __restrict__ x1)
{
    const int pix  = blockIdx.x;
    const int c    = threadIdx.x;
    const int bimg = pix / (HH * WW);
    const int hw   = pix - bimg * HH * WW;
    const int h    = hw / WW;
    const int w    = hw - h * WW;

    float s = dwb[c];
    #pragma unroll
    for (int ky = 0; ky < 3; ky++) {
        const int yy = h + ky - 1;
        if (yy < 0 || yy >= HH) continue;
        #pragma unroll
        for (int kx = 0; kx < 3; kx++) {
            const int xx = w + kx - 1;
            if (xx < 0 || xx >= WW) continue;
            s += xn[((size_t)(bimg * HH + yy) * WW + xx) * CC + c] *
                 dww[(ky * 3 + kx) * CC + c];
        }
    }
    float sm = s, sq = s * s;
    #pragma unroll
    for (int off = 32; off > 0; off >>= 1) {
        sm += __shfl_xor(sm, off, 64);
        sq += __shfl_xor(sq, off, 64);
    }
    __shared__ float red[6];
    const int wid = threadIdx.x >> 6;
    if ((threadIdx.x & 63) == 0) { red[wid] = sm; red[3 + wid] = sq; }
    __syncthreads();
    const float S = red[0] + red[1] + red[2];
    const float Q = red[3] + red[4] + red[5];
    const float mu  = S * (1.f / CC);
    const float var = Q * (1.f / CC) - mu * mu;
    const float rs  = rsqrtf(var + 1e-6f);
    const float y = (s - mu) * rs * lnw[c] + lnb[c];
    x1[(size_t)pix * CC + c] = gelu_exact(y);
}

// ---- fused sampling: softmax(mask logits) + bilinear gather + cfs blend -----
__global__ __launch_bounds__(192) void sample_k(const float* __restrict__ xp,
        const float* __restrict__ x1g, const float* __restrict__ off,
        const float* __restrict__ mlog, const float* __restrict__ cfsw,
        const float* __restrict__ cfsb, float* __restrict__ outb)
{
    __shared__ float x1s[CC];
    __shared__ float offs[CC];
    __shared__ float mls[96];

    const int pix = blockIdx.x;
    const int t   = threadIdx.x;
    const int bimg = pix / (HH * WW);
    const int hw   = pix - bimg * HH * WW;
    const int h    = hw / WW;
    const int w    = hw - h * WW;

    x1s[t]  = x1g[(size_t)pix * CC + t];
    offs[t] = off[(size_t)pix * CC + t];
    if (t < 96) mls[t] = mlog[(size_t)pix * 96 + t];
    __syncthreads();

    const int g = t >> 4;
    const int c = t & 15;

    float lg[8];
    float mx = -1e30f;
    #pragma unroll
    for (int k = 0; k < 8; k++) { lg[k] = mls[g * 8 + k]; mx = fmaxf(mx, lg[k]); }
    float se = 0.f;
    #pragma unroll
    for (int k = 0; k < 8; k++) { lg[k] = expf(lg[k] - mx); se += lg[k]; }
    const float inv = 1.f / se;

    const int GX[8] = {-1, -1, -1, 0, 0, 1, 1, 1};
    const int GY[8] = {-1, 0, 1, -1, 1, -1, 0, 1};
    const size_t imgbase = (size_t)bimg * HH * WW * CC;

    float acc = 0.f;
    #pragma unroll
    for (int k = 0; k < 8; k++) {
        const float px = (float)w + (float)GX[k] + offs[g * 16 + 2 * k];
        const float py = (float)h + (float)GY[k] + offs[g * 16 + 2 * k + 1];
        const float fx = floorf(px), fy = floorf(py);
        const float wx = px - fx,  wy = py - fy;
        const int x0 = (int)fx, y0 = (int)fy;
        float v00 = 0.f, v01 = 0.f, v10 = 0.f, v11 = 0.f;
        if (y0 >= 0 && y0 < HH) {
            if (x0 >= 0 && x0 < WW)         v00 = xp[imgbase + (size_t)(y0 * WW + x0) * CC + t];
            if (x0 + 1 >= 0 && x0 + 1 < WW) v01 = xp[imgbase + (size_t)(y0 * WW + x0 + 1) * CC + t];
        }
        if (y0 + 1 >= 0 && y0 + 1 < HH) {
            if (x0 >= 0 && x0 < WW)         v10 = xp[imgbase + (size_t)((y0 + 1) * WW + x0) * CC + t];
            if (x0 + 1 >= 0 && x0 + 1 < WW) v11 = xp[imgbase + (size_t)((y0 + 1) * WW + x0 + 1) * CC + t];
        }
        const float bil = (1.f - wy) * ((1.f - wx) * v00 + wx * v01)
                        +         wy * ((1.f - wx) * v10 + wx * v11);
        acc += (lg[k] * inv) * bil;
    }

    float part = 0.f;
    #pragma unroll
    for (int j = 0; j < 12; j++)
        part += x1s[c + 16 * j] * cfsw[(size_t)g * CC + c + 16 * j];
    #pragma unroll
    for (int o = 1; o < 16; o <<= 1) part += __shfl_xor(part, o, 64);
    const float cf = 1.f / (1.f + expf(-(part + cfsb[g])));

    const float xpc = xp[(size_t)pix * CC + t];
    outb[(size_t)pix * CC + t] = acc * (1.f - cf) + xpc * cf;
}

// ---- weight prep: pack to MFMA fragment order ------------------------------
// pk[((tile*chunks + c)*64 + lane)*8 + j] = W[k][n],
//   n = 16*tile + (lane&15), k = 32*c + 8*(lane>>4) + j.
// Layout: inpP(36864) | omP(55296) | outP(36864) | fc1P(147456) | fc2P(147456)
__global__ __launch_bounds__(256) void prep_w_k(const float* __restrict__ inpw,
        const float* __restrict__ offw, const float* __restrict__ maskw,
        const float* __restrict__ outpw, const float* __restrict__ fc1w,
        const float* __restrict__ fc2w, bf16* __restrict__ wsB)
{
    const int i = blockIdx.x * 256 + threadIdx.x;
    bf16* inpP = wsB;
    bf16* omP  = wsB + 36864;
    bf16* outP = wsB + 92160;
    bf16* fc1P = wsB + 129024;
    bf16* fc2P = wsB + 276480;
    const int j   = i & 7;
    const int l   = (i >> 3) & 63;
    const int n15 = l & 15, q = l >> 4;
    const int grp = i >> 9;               // tile*chunks + c
    if (i < 36864) {                      // 192x192: 12 tiles x 6 chunks
        const int t = grp / 6, c = grp - t * 6;
        const int n = 16 * t + n15, k = 32 * c + 8 * q + j;
        inpP[i] = f2b(inpw[(size_t)k * 192 + n]);
        outP[i] = f2b(outpw[(size_t)k * 192 + n]);
    }
    if (i < 55296) {                      // 288 cols: 18 tiles x 6 chunks
        const int t = grp / 6, c = grp - t * 6;
        const int n = 16 * t + n15, k = 32 * c + 8 * q + j;
        omP[i] = (n < 192) ? f2b(offw[(size_t)k * 192 + n])
                           : f2b(maskw[(size_t)k * 96 + (n - 192)]);
    }
    if (i < 147456) {
        const int t1 = grp / 6, c1 = grp - t1 * 6;     // fc1: 48 tiles x 6
        const int n1 = 16 * t1 + n15, k1 = 32 * c1 + 8 * q + j;
        fc1P[i] = f2b(fc1w[(size_t)k1 * 768 + n1]);
        const int t2 = grp / 24, c2 = grp - t2 * 24;   // fc2: 12 tiles x 24
        const int n2 = 16 * t2 + n15, k2 = 32 * c2 + 8 * q + j;
        fc2P[i] = f2b(fc2w[(size_t)k2 * 192 + n2]);
    }
}

// ---- generic MFMA GEMM: out[16px][192] = A @ W + bias, 16px/block -----------
__global__ __launch_bounds__(256) void gemm16_k(const float* __restrict__ A,
        const bf16* __restrict__ wP, const float* __restrict__ bias,
        float* __restrict__ out)
{
    __shared__ __align__(16) bf16 xs[16 * XS_STR];
    const int tid = threadIdx.x;
    const int w   = tid >> 6;
    const int l   = tid & 63;
    const int n15 = l & 15;
    const int q   = l >> 4;
    const int p0  = blockIdx.x * 16;

    for (int i = tid; i < 16 * 192; i += 256) {
        const int px = i / 192, k = i - px * 192;
        xs[px * XS_STR + k] = f2b(A[(size_t)(p0 + px) * 192 + k]);
    }
    __syncthreads();

    short8 aF[6];
    #pragma unroll
    for (int c = 0; c < 6; c++)
        aF[c] = *(const short8*)&xs[n15 * XS_STR + c * 32 + q * 8];

    #pragma unroll
    for (int t = 0; t < 3; t++) {
        const int tile = 3 * w + t;
        float4v acc = (float4v){0.f, 0.f, 0.f, 0.f};
        #pragma unroll
        for (int c = 0; c < 6; c++) {
            const short8 bF = *(const short8*)&wP[(size_t)((tile * 6 + c) * 64 + l) * 8];
            acc = __builtin_amdgcn_mfma_f32_16x16x32_bf16(aF[c], bF, acc, 0, 0, 0);
        }
        const int n0 = 16 * tile;
        const float bb = bias[n0 + n15];
        #pragma unroll
        for (int r = 0; r < 4; r++)
            out[(size_t)(p0 + 4 * q + r) * 192 + n0 + n15] = acc[r] + bb;
    }
}

// ---- off+mask fused MFMA GEMM -----------------------------------------------
__global__ __launch_bounds__(256) void gemm_offmask_k(const float* __restrict__ A,
        const bf16* __restrict__ wP, const float* __restrict__ offb,
        const float* __restrict__ maskb, float* __restrict__ offo,
        float* __restrict__ masko)
{
    __shared__ __align__(16) bf16 xs[16 * XS_STR];
    const int tid = threadIdx.x;
    const int w   = tid >> 6;
    const int l   = tid & 63;
    const int n15 = l & 15;
    const int q   = l >> 4;
    const int p0  = blockIdx.x * 16;

    for (int i = tid; i < 16 * 192; i += 256) {
        const int px = i / 192, k = i - px * 192;
        xs[px * XS_STR + k] = f2b(A[(size_t)(p0 + px) * 192 + k]);
    }
    __syncthreads();

    short8 aF[6];
    #pragma unroll
    for (int c = 0; c < 6; c++)
        aF[c] = *(const short8*)&xs[n15 * XS_STR + c * 32 + q * 8];

    for (int t = w; t < 18; t += 4) {
        float4v acc = (float4v){0.f, 0.f, 0.f, 0.f};
        #pragma unroll
        for (int c = 0; c < 6; c++) {
            const short8 bF = *(const short8*)&wP[(size_t)((t * 6 + c) * 64 + l) * 8];
            acc = __builtin_amdgcn_mfma_f32_16x16x32_bf16(aF[c], bF, acc, 0, 0, 0);
        }
        const int n0 = 16 * t;
        if (t < 12) {
            const float bb = offb[n0 + n15];
            #pragma unroll
            for (int r = 0; r < 4; r++)
                offo[(size_t)(p0 + 4 * q + r) * 192 + n0 + n15] = acc[r] + bb;
        } else {
            const int m0 = n0 - 192;
            const float bb = maskb[m0 + n15];
            #pragma unroll
            for (int r = 0; r < 4; r++)
                masko[(size_t)(p0 + 4 * q + r) * 96 + m0 + n15] = acc[r] + bb;
        }
    }
}

// ---- out_proj MFMA GEMM + x2 = x + LN(d,rpn1) + xn2 = LN(x2,norm2) ----------
__global__ __launch_bounds__(256) void gemm_ln2_mfma_k(const float* __restrict__ A,
        const bf16* __restrict__ wP, const float* __restrict__ bias,
        const float* __restrict__ x,
        const float* __restrict__ r1w, const float* __restrict__ r1b,
        const float* __restrict__ n2w, const float* __restrict__ n2b,
        float* __restrict__ x2out, float* __restrict__ xn2out)
{
    __shared__ __align__(16) bf16 xs[16 * XS_STR];
    __shared__ float ps[4][16], pq[4][16], ps2[4][16], pq2[4][16];
    const int tid = threadIdx.x;
    const int w   = tid >> 6;
    const int l   = tid & 63;
    const int n15 = l & 15;
    const int q   = l >> 4;
    const int p0  = blockIdx.x * 16;

    for (int i = tid; i < 16 * 192; i += 256) {
        const int px = i / 192, k = i - px * 192;
        xs[px * XS_STR + k] = f2b(A[(size_t)(p0 + px) * 192 + k]);
    }
    __syncthreads();

    short8 aF[6];
    #pragma unroll
    for (int c = 0; c < 6; c++)
        aF[c] = *(const short8*)&xs[n15 * XS_STR + c * 32 + q * 8];

    float4v acc[3];
    #pragma unroll
    for (int t = 0; t < 3; t++) {
        const int tile = 3 * w + t;
        acc[t] = (float4v){0.f, 0.f, 0.f, 0.f};
        #pragma unroll
        for (int c = 0; c < 6; c++) {
            const short8 bF = *(const short8*)&wP[(size_t)((tile * 6 + c) * 64 + l) * 8];
            acc[t] = __builtin_amdgcn_mfma_f32_16x16x32_bf16(aF[c], bF, acc[t], 0, 0, 0);
        }
        const float bb = bias[16 * tile + n15];
        #pragma unroll
        for (int r = 0; r < 4; r++) acc[t][r] += bb;
    }

    #pragma unroll
    for (int r = 0; r < 4; r++) {
        float sp = acc[0][r] + acc[1][r] + acc[2][r];
        float qp = acc[0][r]*acc[0][r] + acc[1][r]*acc[1][r] + acc[2][r]*acc[2][r];
        #pragma unroll
        for (int o = 1; o < 16; o <<= 1) {
            sp += __shfl_xor(sp, o, 64);
            qp += __shfl_xor(qp, o, 64);
        }
        if (n15 == 0) { ps[w][4 * q + r] = sp; pq[w][4 * q + r] = qp; }
    }
    __syncthreads();

    float x2v[3][4];
    #pragma unroll
    for (int r = 0; r < 4; r++) {
        const int row = 4 * q + r;
        const float s  = ps[0][row] + ps[1][row] + ps[2][row] + ps[3][row];
        const float qq = pq[0][row] + pq[1][row] + pq[2][row] + pq[3][row];
        const float mu  = s * (1.f / CC);
        const float var = qq * (1.f / CC) - mu * mu;
        const float rs  = rsqrtf(var + 1e-5f);
        const size_t grow = p0 + row;
        #pragma unroll
        for (int t = 0; t < 3; t++) {
            const int col = 48 * w + 16 * t + n15;
            x2v[t][r] = x[grow * CC + col] + (acc[t][r] - mu) * rs * r1w[col] + r1b[col];
        }
    }

    #pragma unroll
    for (int r = 0; r < 4; r++) {
        float sp = x2v[0][r] + x2v[1][r] + x2v[2][r];
        float qp = x2v[0][r]*x2v[0][r] + x2v[1][r]*x2v[1][r] + x2v[2][r]*x2v[2][r];
        #pragma unroll
        for (int o = 1; o < 16; o <<= 1) {
            sp += __shfl_xor(sp, o, 64);
            qp += __shfl_xor(qp, o, 64);
        }
        if (n15 == 0) { ps2[w][4 * q + r] = sp; pq2[w][4 * q + r] = qp; }
    }
    __syncthreads();

    #pragma unroll
    for (int r = 0; r < 4; r++) {
        const int row = 4 * q + r;
        const float s  = ps2[0][row] + ps2[1][row] + ps2[2][row] + ps2[3][row];
        const float qq = pq2[0][row] + pq2[1][row] + pq2[2][row] + pq2[3][row];
        const float mu  = s * (1.f / CC);
        const float var = qq * (1.f / CC) - mu * mu;
        const float rs  = rsqrtf(var + 1e-5f);
        const size_t grow = p0 + row;
        #pragma unroll
        for (int t = 0; t < 3; t++) {
            const int col = 48 * w + 16 * t + n15;
            x2out[grow * CC + col]  = x2v[t][r];
            xn2out[grow * CC + col] = (x2v[t][r] - mu) * rs * n2w[col] + n2b[col];
        }
    }
}

// ---- MFMA MLP: out = x2 + LN(gelu(xn2@fc1+b1)@fc2+b2, rpn2), 16px/block -----
__global__ __launch_bounds__(256) void mlp_mfma16_k(const float* __restrict__ xn2,
        const bf16* __restrict__ fc1P, const float* __restrict__ fc1b,
        const bf16* __restrict__ fc2P, const float* __restrict__ fc2b,
        const float* __restrict__ x2, const float* __restrict__ r2w,
        const float* __restrict__ r2b, float* __restrict__ out)
{
    __shared__ __align__(16) bf16 xs[16 * XS_STR];   // 6.4 KB
    __shared__ __align__(16) bf16 h1[16 * H1S];      // 24.8 KB
    __shared__ float ps[4][16], pq[4][16];

    const int tid = threadIdx.x;
    const int w   = tid >> 6;
    const int l   = tid & 63;
    const int n15 = l & 15;
    const int q   = l >> 4;
    const int p0  = blockIdx.x * 16;

    for (int i = tid; i < 16 * 192; i += 256) {
        const int px = i / 192, k = i - px * 192;
        xs[px * XS_STR + k] = f2b(xn2[(size_t)(p0 + px) * 192 + k]);
    }
    __syncthreads();

    short8 aF[6];
    #pragma unroll
    for (int c = 0; c < 6; c++)
        aF[c] = *(const short8*)&xs[n15 * XS_STR + c * 32 + q * 8];

    // fc1 + GELU -> h1 (wave w covers cols 192w..192w+191 = tiles 12w..12w+11)
    #pragma unroll
    for (int t1 = 0; t1 < 12; t1++) {
        const int tile = 12 * w + t1;
        float4v a1 = (float4v){0.f, 0.f, 0.f, 0.f};
        #pragma unroll
        for (int c = 0; c < 6; c++) {
            const short8 bF = *(const short8*)&fc1P[(size_t)((tile * 6 + c) * 64 + l) * 8];
            a1 = __builtin_amdgcn_mfma_f32_16x16x32_bf16(aF[c], bF, a1, 0, 0, 0);
        }
        const int n0 = 16 * tile;
        const float bb = fc1b[n0 + n15];
        #pragma unroll
        for (int r = 0; r < 4; r++)
            h1[(4 * q + r) * H1S + n0 + n15] = f2b(gelu_exact(a1[r] + bb));
    }
    __syncthreads();

    // fc2: wave w covers out cols 48w..48w+47 (tiles 3w..3w+2), K = 768
    float4v acc2[3];
    #pragma unroll
    for (int t = 0; t < 3; t++) acc2[t] = (float4v){0.f, 0.f, 0.f, 0.f};
    #pragma unroll 4
    for (int kc = 0; kc < 24; kc++) {
        const short8 a2 = *(const short8*)&h1[n15 * H1S + kc * 32 + q * 8];
        #pragma unroll
        for (int t = 0; t < 3; t++) {
            const int tile = 3 * w + t;
            const short8 bF = *(const short8*)&fc2P[(size_t)((tile * 24 + kc) * 64 + l) * 8];
            acc2[t] = __builtin_amdgcn_mfma_f32_16x16x32_bf16(a2, bF, acc2[t], 0, 0, 0);
        }
    }
    #pragma unroll
    for (int t = 0; t < 3; t++) {
        const float bb = fc2b[48 * w + 16 * t + n15];
        #pragma unroll
        for (int r = 0; r < 4; r++) acc2[t][r] += bb;
    }

    // LN(rpn2) partials across waves
    #pragma unroll
    for (int r = 0; r < 4; r++) {
        float sp = acc2[0][r] + acc2[1][r] + acc2[2][r];
        float qp = acc2[0][r]*acc2[0][r] + acc2[1][r]*acc2[1][r] + acc2[2][r]*acc2[2][r];
        #pragma unroll
        for (int o = 1; o < 16; o <<= 1) {
            sp += __shfl_xor(sp, o, 64);
            qp += __shfl_xor(qp, o, 64);
        }
        if (n15 == 0) { ps[w][4 * q + r] = sp; pq[w][4 * q + r] = qp; }
    }
    __syncthreads();

    #pragma unroll
    for (int r = 0; r < 4; r++) {
        const int row = 4 * q + r;
        const float s  = ps[0][row] + ps[1][row] + ps[2][row] + ps[3][row];
        const float qq = pq[0][row] + pq[1][row] + pq[2][row] + pq[3][row];
        const float mu  = s * (1.f / CC);
        const float var = qq * (1.f / CC) - mu * mu;
        const float rs  = rsqrtf(var + 1e-5f);
        const size_t grow = p0 + row;
        #pragma unroll
        for (int t = 0; t < 3; t++) {
            const int col = 48 * w + 16 * t + n15;
            out[grow * CC + col] = x2[grow * CC + col]
                                 + (acc2[t][r] - mu) * rs * r2w[col] + r2b[col];
        }
    }
}

extern "C" void kernel_launch(void* const* d_in, const int* in_sizes, int n_in,
                              void* d_out, int out_size, void* d_ws, size_t ws_size,
                              hipStream_t stream) {
    const float* x      = (const float*)d_in[0];
    const float* n1w    = (const float*)d_in[1];
    const float* n1b    = (const float*)d_in[2];
    const float* n2w    = (const float*)d_in[3];
    const float* n2b    = (const float*)d_in[4];
    const float* rpn1w  = (const float*)d_in[5];
    const float* rpn1b  = (const float*)d_in[6];
    const float* rpn2w  = (const float*)d_in[7];
    const float* rpn2b  = (const float*)d_in[8];
    const float* inpw   = (const float*)d_in[9];
    const float* inpb   = (const float*)d_in[10];
    const float* dww    = (const float*)d_in[11];
    const float* dwb    = (const float*)d_in[12];
    const float* dwlnw  = (const float*)d_in[13];
    const float* dwlnb  = (const float*)d_in[14];
    const float* offw   = (const float*)d_in[15];
    const float* offb   = (const float*)d_in[16];
    const float* maskw  = (const float*)d_in[17];
    const float* maskb  = (const float*)d_in[18];
    const float* cfsw   = (const float*)d_in[19];
    const float* cfsb   = (const float*)d_in[20];
    const float* outpw  = (const float*)d_in[21];
    const float* outpb  = (const float*)d_in[22];
    const float* fc1w   = (const float*)d_in[23];
    const float* fc1b   = (const float*)d_in[24];
    const float* fc2w   = (const float*)d_in[25];
    const float* fc2b   = (const float*)d_in[26];

    const int N = NPIX;                       // 12544
    const size_t NP = (size_t)N * CC;
    float* F0 = (float*)d_ws;                 // xn -> blended
    float* F1 = F0 + NP;                      // xp -> x2
    float* F2 = F1 + NP;                      // off
    float* F3 = F2 + NP;                      // x1 -> xn2
    float* Fm = F3 + NP;                      // mask logits N*96
    bf16* wsB = (bf16*)(Fm + (size_t)N * 96); // packed bf16 weights
    const bf16* inpP = wsB;
    const bf16* omP  = wsB + 36864;
    const bf16* outP = wsB + 92160;
    const bf16* fc1P = wsB + 129024;
    const bf16* fc2P = wsB + 276480;

    const int lnG = N / 4;     // 3136
    const int g16 = N / 16;    // 784

    // 0. weight prep (bf16, fragment-packed)
    prep_w_k<<<576, 256, 0, stream>>>(inpw, offw, maskw, outpw, fc1w, fc2w, wsB);
    // 1. xn = LN(x, norm1)                         -> F0
    ln4_k<<<lnG, 256, 0, stream>>>(x, n1w, n1b, F0, 1e-5f);
    // 2. xp = xn @ in_proj + b                     -> F1
    gemm16_k<<<g16, 256, 0, stream>>>(F0, inpP, inpb, F1);
    // 3. x1 = gelu(LN(dwconv(xn), 1e-6))           -> F3
    dwconv_ln_gelu_k<<<N, 192, 0, stream>>>(F0, dww, dwb, dwlnw, dwlnb, F3);
    // 4. off -> F2, mask logits -> Fm (fused, shared A-tile)
    gemm_offmask_k<<<g16, 256, 0, stream>>>(F3, omP, offb, maskb, F2, Fm);
    // 5. blended = sample(xp, x1, off, mlog)       -> F0
    sample_k<<<N, 192, 0, stream>>>(F1, F3, F2, Fm, cfsw, cfsb, F0);
    // 6. x2 = x + LN(blended@out_proj+b, rpn1); xn2 = LN(x2, norm2)
    gemm_ln2_mfma_k<<<g16, 256, 0, stream>>>(F0, outP, outpb, x, rpn1w, rpn1b,
                                             n2w, n2b, F1, F3);
    // 7. out = x2 + LN(gelu(xn2@fc1)@fc2, rpn2)    -> d_out
    mlp_mfma16_k<<<g16, 256, 0, stream>>>(F3, fc1P, fc1b, fc2P, fc2b,
                                          F1, rpn2w, rpn2b, (float*)d_out);
}

// Round 14
// 245.877 us; speedup vs baseline: 2.0797x; 1.0737x over previous
//
#include <hip/hip_runtime.h>
#include <hip/hip_bf16.h>
#include <math.h>

// InternImage DCNv3 block forward — round 14: vectorized sample + dwconv.
// r13: 264us, leader sample_k 70us (VMEM-instr + redundant-VALU bound:
// 32 scalar gathers/thread, softmax replicated 16x/group).  r14: float4
// channel quads in sample_k (4px/block, 48thr/px) and dwconv (wave=pixel,
// 48 conv lanes).  All GEMM/MFMA kernels unchanged from r13.
// ws: F0..F3 (N*192 fp32) | Fm (N*96 fp32) | packed bf16 weights (848KB).

#define BATCH 4
#define HH 56
#define WW 56
#define CC 192
#define NPIX (BATCH * HH * WW)   // 12544
#define XS_STR 200               // 192+8: 400B row stride, 16B aligned
#define H1S 776                  // 768+8: 1552B row stride, 16B aligned

typedef __hip_bfloat16 bf16;
typedef __attribute__((ext_vector_type(8))) short short8;
typedef __attribute__((ext_vector_type(4))) float float4v;

__device__ __forceinline__ float gelu_exact(float x) {
    return 0.5f * x * (1.f + erff(x * 0.70710678118654752f));
}
__device__ __forceinline__ bf16 f2b(float f) { return __float2bfloat16(f); }

// ---------------- LN over C=192, one wave per pixel, 4 px/block --------------
__global__ __launch_bounds__(256) void ln4_k(const float* __restrict__ X,
        const float* __restrict__ w, const float* __restrict__ b,
        float* __restrict__ out, float eps)
{
    const int pix  = blockIdx.x * 4 + (threadIdx.x >> 6);
    const int lane = threadIdx.x & 63;
    const size_t base = (size_t)pix * CC;
    float v[3];
    #pragma unroll
    for (int i = 0; i < 3; i++) v[i] = X[base + lane + 64 * i];
    float s = v[0] + v[1] + v[2];
    float q = v[0]*v[0] + v[1]*v[1] + v[2]*v[2];
    #pragma unroll
    for (int off = 32; off > 0; off >>= 1) {
        s += __shfl_xor(s, off, 64);
        q += __shfl_xor(q, off, 64);
    }
    const float mu  = s * (1.f / CC);
    const float var = q * (1.f / CC) - mu * mu;
    const float rs  = rsqrtf(var + eps);
    #pragma unroll
    for (int i = 0; i < 3; i++) {
        const int c = lane + 64 * i;
        out[base + c] = (v[i] - mu) * rs * w[c] + b[c];
    }
}

// ------- dwconv 3x3 (SAME) + LN(1e-6) + GELU: 4px/block, float4 channels -----
__global__ __launch_bounds__(256) void dwconv_ln_gelu_k(
        const float* __restrict__ xn, const float* __restrict__ dww,
        const float* __restrict__ dwb, const float* __restrict__ lnw,
        const float* __restrict__ lnb, float* __restrict__ x1)
{
    __shared__ float cv[4][192];
    const int t    = threadIdx.x;
    const int ws   = t >> 6;            // pixel slot (wave)
    const int l    = t & 63;
    const int pix  = blockIdx.x * 4 + ws;
    const int bimg = pix / (HH * WW);
    const int hw   = pix - bimg * HH * WW;
    const int h    = hw / WW;
    const int wx   = hw - h * WW;

    if (l < 48) {
        const int c0 = l * 4;
        float4 acc = *(const float4*)&dwb[c0];
        #pragma unroll
        for (int ky = 0; ky < 3; ky++) {
            const int yy = h + ky - 1;
            if (yy < 0 || yy >= HH) continue;
            #pragma unroll
            for (int kx = 0; kx < 3; kx++) {
                const int xx = wx + kx - 1;
                if (xx < 0 || xx >= WW) continue;
                const float4 a = *(const float4*)&xn[((size_t)(bimg * HH + yy) * WW + xx) * CC + c0];
                const float4 ww = *(const float4*)&dww[(ky * 3 + kx) * CC + c0];
                acc.x += a.x * ww.x; acc.y += a.y * ww.y;
                acc.z += a.z * ww.z; acc.w += a.w * ww.w;
            }
        }
        *(float4*)&cv[ws][c0] = acc;
    }
    __syncthreads();

    float v[3];
    #pragma unroll
    for (int i = 0; i < 3; i++) v[i] = cv[ws][l + 64 * i];
    float s = v[0] + v[1] + v[2];
    float q = v[0]*v[0] + v[1]*v[1] + v[2]*v[2];
    #pragma unroll
    for (int off = 32; off > 0; off >>= 1) {
        s += __shfl_xor(s, off, 64);
        q += __shfl_xor(q, off, 64);
    }
    const float mu  = s * (1.f / CC);
    const float var = q * (1.f / CC) - mu * mu;
    const float rs  = rsqrtf(var + 1e-6f);
    #pragma unroll
    for (int i = 0; i < 3; i++) {
        const int c = l + 64 * i;
        x1[(size_t)pix * CC + c] = gelu_exact((v[i] - mu) * rs * lnw[c] + lnb[c]);
    }
}

// ---- sampling: 4px/block, 48thr/px, float4 channel quads --------------------
__global__ __launch_bounds__(192) void sample_k(const float* __restrict__ xp,
        const float* __restrict__ x1g, const float* __restrict__ off,
        const float* __restrict__ mlog, const float* __restrict__ cfsw,
        const float* __restrict__ cfsb, float* __restrict__ outb)
{
    __shared__ float x1s[4][192];
    __shared__ float offs[4][192];
    __shared__ float mls[4][96];

    const int t  = threadIdx.x;
    const int pb = blockIdx.x * 4;

    for (int i = t; i < 4 * 192; i += 192) {
        const int p = i >> 8 >= 0 ? i / 192 : 0;  // i/192
        const int c = i - (i / 192) * 192;
        x1s[i / 192][c]  = x1g[(size_t)(pb + i / 192) * CC + c];
        offs[i / 192][c] = off[(size_t)(pb + i / 192) * CC + c];
        (void)p;
    }
    for (int i = t; i < 4 * 96; i += 192) {
        const int p = i / 96, c = i - p * 96;
        mls[p][c] = mlog[(size_t)(pb + p) * 96 + c];
    }
    __syncthreads();

    const int p   = t / 48;          // pixel slot
    const int s   = t - p * 48;
    const int g   = s >> 2;          // group 0..11
    const int c4  = s & 3;           // channel quad in group
    const int ch0 = g * 16 + c4 * 4;
    const int pix = pb + p;
    const int bimg = pix / (HH * WW);
    const int hw   = pix - bimg * HH * WW;
    const int h    = hw / WW;
    const int w    = hw - h * WW;

    // softmax over this group's 8 logits (redundant x4 — cheap)
    float lg[8];
    float mx = -1e30f;
    #pragma unroll
    for (int k = 0; k < 8; k++) { lg[k] = mls[p][g * 8 + k]; mx = fmaxf(mx, lg[k]); }
    float se = 0.f;
    #pragma unroll
    for (int k = 0; k < 8; k++) { lg[k] = expf(lg[k] - mx); se += lg[k]; }
    const float inv = 1.f / se;

    const int GX[8] = {-1, -1, -1, 0, 0, 1, 1, 1};
    const int GY[8] = {-1, 0, 1, -1, 1, -1, 0, 1};
    const size_t imgbase = (size_t)bimg * HH * WW * CC;

    float4 acc = {0.f, 0.f, 0.f, 0.f};
    #pragma unroll
    for (int k = 0; k < 8; k++) {
        const float px = (float)w + (float)GX[k] + offs[p][g * 16 + 2 * k];
        const float py = (float)h + (float)GY[k] + offs[p][g * 16 + 2 * k + 1];
        const float fx = floorf(px), fy = floorf(py);
        const float wxf = px - fx, wyf = py - fy;
        const int x0 = (int)fx, y0 = (int)fy;
        float4 v00 = {0,0,0,0}, v01 = {0,0,0,0}, v10 = {0,0,0,0}, v11 = {0,0,0,0};
        if (y0 >= 0 && y0 < HH) {
            if (x0 >= 0 && x0 < WW)
                v00 = *(const float4*)&xp[imgbase + (size_t)(y0 * WW + x0) * CC + ch0];
            if (x0 + 1 >= 0 && x0 + 1 < WW)
                v01 = *(const float4*)&xp[imgbase + (size_t)(y0 * WW + x0 + 1) * CC + ch0];
        }
        if (y0 + 1 >= 0 && y0 + 1 < HH) {
            if (x0 >= 0 && x0 < WW)
                v10 = *(const float4*)&xp[imgbase + (size_t)((y0 + 1) * WW + x0) * CC + ch0];
            if (x0 + 1 >= 0 && x0 + 1 < WW)
                v11 = *(const float4*)&xp[imgbase + (size_t)((y0 + 1) * WW + x0 + 1) * CC + ch0];
        }
        const float w00 = (1.f - wyf) * (1.f - wxf), w01 = (1.f - wyf) * wxf;
        const float w10 = wyf * (1.f - wxf),         w11 = wyf * wxf;
        const float mk = lg[k] * inv;
        acc.x += mk * (w00 * v00.x + w01 * v01.x + w10 * v10.x + w11 * v11.x);
        acc.y += mk * (w00 * v00.y + w01 * v01.y + w10 * v10.y + w11 * v11.y);
        acc.z += mk * (w00 * v00.z + w01 * v01.z + w10 * v10.z + w11 * v11.z);
        acc.w += mk * (w00 * v00.w + w01 * v01.w + w10 * v10.w + w11 * v11.w);
    }

    // cfs = sigmoid(x1 . cfs_w[g] + cfs_b[g]); split over the 4-quad, xor-reduce
    float part = 0.f;
    #pragma unroll
    for (int j = 0; j < 48; j++)
        part += x1s[p][4 * j + c4] * cfsw[(size_t)g * CC + 4 * j + c4];
    part += __shfl_xor(part, 1, 64);
    part += __shfl_xor(part, 2, 64);
    const float cf = 1.f / (1.f + expf(-(part + cfsb[g])));

    const float4 xpc = *(const float4*)&xp[(size_t)pix * CC + ch0];
    float4 o;
    o.x = acc.x * (1.f - cf) + xpc.x * cf;
    o.y = acc.y * (1.f - cf) + xpc.y * cf;
    o.z = acc.z * (1.f - cf) + xpc.z * cf;
    o.w = acc.w * (1.f - cf) + xpc.w * cf;
    *(float4*)&outb[(size_t)pix * CC + ch0] = o;
}

// ---- weight prep: pack to MFMA fragment order ------------------------------
__global__ __launch_bounds__(256) void prep_w_k(const float* __restrict__ inpw,
        const float* __restrict__ offw, const float* __restrict__ maskw,
        const float* __restrict__ outpw, const float* __restrict__ fc1w,
        const float* __restrict__ fc2w, bf16* __restrict__ wsB)
{
    const int i = blockIdx.x * 256 + threadIdx.x;
    bf16* inpP = wsB;
    bf16* omP  = wsB + 36864;
    bf16* outP = wsB + 92160;
    bf16* fc1P = wsB + 129024;
    bf16* fc2P = wsB + 276480;
    const int j   = i & 7;
    const int l   = (i >> 3) & 63;
    const int n15 = l & 15, q = l >> 4;
    const int grp = i >> 9;
    if (i < 36864) {
        const int t = grp / 6, c = grp - t * 6;
        const int n = 16 * t + n15, k = 32 * c + 8 * q + j;
        inpP[i] = f2b(inpw[(size_t)k * 192 + n]);
        outP[i] = f2b(outpw[(size_t)k * 192 + n]);
    }
    if (i < 55296) {
        const int t = grp / 6, c = grp - t * 6;
        const int n = 16 * t + n15, k = 32 * c + 8 * q + j;
        omP[i] = (n < 192) ? f2b(offw[(size_t)k * 192 + n])
                           : f2b(maskw[(size_t)k * 96 + (n - 192)]);
    }
    if (i < 147456) {
        const int t1 = grp / 6, c1 = grp - t1 * 6;
        const int n1 = 16 * t1 + n15, k1 = 32 * c1 + 8 * q + j;
        fc1P[i] = f2b(fc1w[(size_t)k1 * 768 + n1]);
        const int t2 = grp / 24, c2 = grp - t2 * 24;
        const int n2 = 16 * t2 + n15, k2 = 32 * c2 + 8 * q + j;
        fc2P[i] = f2b(fc2w[(size_t)k2 * 192 + n2]);
    }
}

// ---- generic MFMA GEMM: out[16px][192] = A @ W + bias, 16px/block -----------
__global__ __launch_bounds__(256) void gemm16_k(const float* __restrict__ A,
        const bf16* __restrict__ wP, const float* __restrict__ bias,
        float* __restrict__ out)
{
    __shared__ __align__(16) bf16 xs[16 * XS_STR];
    const int tid = threadIdx.x;
    const int w   = tid >> 6;
    const int l   = tid & 63;
    const int n15 = l & 15;
    const int q   = l >> 4;
    const int p0  = blockIdx.x * 16;

    for (int i = tid; i < 16 * 192; i += 256) {
        const int px = i / 192, k = i - px * 192;
        xs[px * XS_STR + k] = f2b(A[(size_t)(p0 + px) * 192 + k]);
    }
    __syncthreads();

    short8 aF[6];
    #pragma unroll
    for (int c = 0; c < 6; c++)
        aF[c] = *(const short8*)&xs[n15 * XS_STR + c * 32 + q * 8];

    #pragma unroll
    for (int t = 0; t < 3; t++) {
        const int tile = 3 * w + t;
        float4v acc = (float4v){0.f, 0.f, 0.f, 0.f};
        #pragma unroll
        for (int c = 0; c < 6; c++) {
            const short8 bF = *(const short8*)&wP[(size_t)((tile * 6 + c) * 64 + l) * 8];
            acc = __builtin_amdgcn_mfma_f32_16x16x32_bf16(aF[c], bF, acc, 0, 0, 0);
        }
        const int n0 = 16 * tile;
        const float bb = bias[n0 + n15];
        #pragma unroll
        for (int r = 0; r < 4; r++)
            out[(size_t)(p0 + 4 * q + r) * 192 + n0 + n15] = acc[r] + bb;
    }
}

// ---- off+mask fused MFMA GEMM -----------------------------------------------
__global__ __launch_bounds__(256) void gemm_offmask_k(const float* __restrict__ A,
        const bf16* __restrict__ wP, const float* __restrict__ offb,
        const float* __restrict__ maskb, float* __restrict__ offo,
        float* __restrict__ masko)
{
    __shared__ __align__(16) bf16 xs[16 * XS_STR];
    const int tid = threadIdx.x;
    const int w   = tid >> 6;
    const int l   = tid & 63;
    const int n15 = l & 15;
    const int q   = l >> 4;
    const int p0  = blockIdx.x * 16;

    for (int i = tid; i < 16 * 192; i += 256) {
        const int px = i / 192, k = i - px * 192;
        xs[px * XS_STR + k] = f2b(A[(size_t)(p0 + px) * 192 + k]);
    }
    __syncthreads();

    short8 aF[6];
    #pragma unroll
    for (int c = 0; c < 6; c++)
        aF[c] = *(const short8*)&xs[n15 * XS_STR + c * 32 + q * 8];

    for (int t = w; t < 18; t += 4) {
        float4v acc = (float4v){0.f, 0.f, 0.f, 0.f};
        #pragma unroll
        for (int c = 0; c < 6; c++) {
            const short8 bF = *(const short8*)&wP[(size_t)((t * 6 + c) * 64 + l) * 8];
            acc = __builtin_amdgcn_mfma_f32_16x16x32_bf16(aF[c], bF, acc, 0, 0, 0);
        }
        const int n0 = 16 * t;
        if (t < 12) {
            const float bb = offb[n0 + n15];
            #pragma unroll
            for (int r = 0; r < 4; r++)
                offo[(size_t)(p0 + 4 * q + r) * 192 + n0 + n15] = acc[r] + bb;
        } else {
            const int m0 = n0 - 192;
            const float bb = maskb[m0 + n15];
            #pragma unroll
            for (int r = 0; r < 4; r++)
                masko[(size_t)(p0 + 4 * q + r) * 96 + m0 + n15] = acc[r] + bb;
        }
    }
}

// ---- out_proj MFMA GEMM + x2 = x + LN(d,rpn1) + xn2 = LN(x2,norm2) ----------
__global__ __launch_bounds__(256) void gemm_ln2_mfma_k(const float* __restrict__ A,
        const bf16* __restrict__ wP, const float* __restrict__ bias,
        const float* __restrict__ x,
        const float* __restrict__ r1w, const float* __restrict__ r1b,
        const float* __restrict__ n2w, const float* __restrict__ n2b,
        float* __restrict__ x2out, float* __restrict__ xn2out)
{
    __shared__ __align__(16) bf16 xs[16 * XS_STR];
    __shared__ float ps[4][16], pq[4][16], ps2[4][16], pq2[4][16];
    const int tid = threadIdx.x;
    const int w   = tid >> 6;
    const int l   = tid & 63;
    const int n15 = l & 15;
    const int q   = l >> 4;
    const int p0  = blockIdx.x * 16;

    for (int i = tid; i < 16 * 192; i += 256) {
        const int px = i / 192, k = i - px * 192;
        xs[px * XS_STR + k] = f2b(A[(size_t)(p0 + px) * 192 + k]);
    }
    __syncthreads();

    short8 aF[6];
    #pragma unroll
    for (int c = 0; c < 6; c++)
        aF[c] = *(const short8*)&xs[n15 * XS_STR + c * 32 + q * 8];

    float4v acc[3];
    #pragma unroll
    for (int t = 0; t < 3; t++) {
        const int tile = 3 * w + t;
        acc[t] = (float4v){0.f, 0.f, 0.f, 0.f};
        #pragma unroll
        for (int c = 0; c < 6; c++) {
            const short8 bF = *(const short8*)&wP[(size_t)((tile * 6 + c) * 64 + l) * 8];
            acc[t] = __builtin_amdgcn_mfma_f32_16x16x32_bf16(aF[c], bF, acc[t], 0, 0, 0);
        }
        const float bb = bias[16 * tile + n15];
        #pragma unroll
        for (int r = 0; r < 4; r++) acc[t][r] += bb;
    }

    #pragma unroll
    for (int r = 0; r < 4; r++) {
        float sp = acc[0][r] + acc[1][r] + acc[2][r];
        float qp = acc[0][r]*acc[0][r] + acc[1][r]*acc[1][r] + acc[2][r]*acc[2][r];
        #pragma unroll
        for (int o = 1; o < 16; o <<= 1) {
            sp += __shfl_xor(sp, o, 64);
            qp += __shfl_xor(qp, o, 64);
        }
        if (n15 == 0) { ps[w][4 * q + r] = sp; pq[w][4 * q + r] = qp; }
    }
    __syncthreads();

    float x2v[3][4];
    #pragma unroll
    for (int r = 0; r < 4; r++) {
        const int row = 4 * q + r;
        const float s  = ps[0][row] + ps[1][row] + ps[2][row] + ps[3][row];
        const float qq = pq[0][row] + pq[1][row] + pq[2][row] + pq[3][row];
        const float mu  = s * (1.f / CC);
        const float var = qq * (1.f / CC) - mu * mu;
        const float rs  = rsqrtf(var + 1e-5f);
        const size_t grow = p0 + row;
        #pragma unroll
        for (int t = 0; t < 3; t++) {
            const int col = 48 * w + 16 * t + n15;
            x2v[t][r] = x[grow * CC + col] + (acc[t][r] - mu) * rs * r1w[col] + r1b[col];
        }
    }

    #pragma unroll
    for (int r = 0; r < 4; r++) {
        float sp = x2v[0][r] + x2v[1][r] + x2v[2][r];
        float qp = x2v[0][r]*x2v[0][r] + x2v[1][r]*x2v[1][r] + x2v[2][r]*x2v[2][r];
        #pragma unroll
        for (int o = 1; o < 16; o <<= 1) {
            sp += __shfl_xor(sp, o, 64);
            qp += __shfl_xor(qp, o, 64);
        }
        if (n15 == 0) { ps2[w][4 * q + r] = sp; pq2[w][4 * q + r] = qp; }
    }
    __syncthreads();

    #pragma unroll
    for (int r = 0; r < 4; r++) {
        const int row = 4 * q + r;
        const float s  = ps2[0][row] + ps2[1][row] + ps2[2][row] + ps2[3][row];
        const float qq = pq2[0][row] + pq2[1][row] + pq2[2][row] + pq2[3][row];
        const float mu  = s * (1.f / CC);
        const float var = qq * (1.f / CC) - mu * mu;
        const float rs  = rsqrtf(var + 1e-5f);
        const size_t grow = p0 + row;
        #pragma unroll
        for (int t = 0; t < 3; t++) {
            const int col = 48 * w + 16 * t + n15;
            x2out[grow * CC + col]  = x2v[t][r];
            xn2out[grow * CC + col] = (x2v[t][r] - mu) * rs * n2w[col] + n2b[col];
        }
    }
}

// ---- MFMA MLP: out = x2 + LN(gelu(xn2@fc1+b1)@fc2+b2, rpn2), 16px/block -----
__global__ __launch_bounds__(256) void mlp_mfma16_k(const float* __restrict__ xn2,
        const bf16* __restrict__ fc1P, const float* __restrict__ fc1b,
        const bf16* __restrict__ fc2P, const float* __restrict__ fc2b,
        const float* __restrict__ x2, const float* __restrict__ r2w,
        const float* __restrict__ r2b, float* __restrict__ out)
{
    __shared__ __align__(16) bf16 xs[16 * XS_STR];
    __shared__ __align__(16) bf16 h1[16 * H1S];
    __shared__ float ps[4][16], pq[4][16];

    const int tid = threadIdx.x;
    const int w   = tid >> 6;
    const int l   = tid & 63;
    const int n15 = l & 15;
    const int q   = l >> 4;
    const int p0  = blockIdx.x * 16;

    for (int i = tid; i < 16 * 192; i += 256) {
        const int px = i / 192, k = i - px * 192;
        xs[px * XS_STR + k] = f2b(xn2[(size_t)(p0 + px) * 192 + k]);
    }
    __syncthreads();

    short8 aF[6];
    #pragma unroll
    for (int c = 0; c < 6; c++)
        aF[c] = *(const short8*)&xs[n15 * XS_STR + c * 32 + q * 8];

    #pragma unroll
    for (int t1 = 0; t1 < 12; t1++) {
        const int tile = 12 * w + t1;
        float4v a1 = (float4v){0.f, 0.f, 0.f, 0.f};
        #pragma unroll
        for (int c = 0; c < 6; c++) {
            const short8 bF = *(const short8*)&fc1P[(size_t)((tile * 6 + c) * 64 + l) * 8];
            a1 = __builtin_amdgcn_mfma_f32_16x16x32_bf16(aF[c], bF, a1, 0, 0, 0);
        }
        const int n0 = 16 * tile;
        const float bb = fc1b[n0 + n15];
        #pragma unroll
        for (int r = 0; r < 4; r++)
            h1[(4 * q + r) * H1S + n0 + n15] = f2b(gelu_exact(a1[r] + bb));
    }
    __syncthreads();

    float4v acc2[3];
    #pragma unroll
    for (int t = 0; t < 3; t++) acc2[t] = (float4v){0.f, 0.f, 0.f, 0.f};
    #pragma unroll 4
    for (int kc = 0; kc < 24; kc++) {
        const short8 a2 = *(const short8*)&h1[n15 * H1S + kc * 32 + q * 8];
        #pragma unroll
        for (int t = 0; t < 3; t++) {
            const int tile = 3 * w + t;
            const short8 bF = *(const short8*)&fc2P[(size_t)((tile * 24 + kc) * 64 + l) * 8];
            acc2[t] = __builtin_amdgcn_mfma_f32_16x16x32_bf16(a2, bF, acc2[t], 0, 0, 0);
        }
    }
    #pragma unroll
    for (int t = 0; t < 3; t++) {
        const float bb = fc2b[48 * w + 16 * t + n15];
        #pragma unroll
        for (int r = 0; r < 4; r++) acc2[t][r] += bb;
    }

    #pragma unroll
    for (int r = 0; r < 4; r++) {
        float sp = acc2[0][r] + acc2[1][r] + acc2[2][r];
        float qp = acc2[0][r]*acc2[0][r] + acc2[1][r]*acc2[1][r] + acc2[2][r]*acc2[2][r];
        #pragma unroll
        for (int o = 1; o < 16; o <<= 1) {
            sp += __shfl_xor(sp, o, 64);
            qp += __shfl_xor(qp, o, 64);
        }
        if (n15 == 0) { ps[w][4 * q + r] = sp; pq[w][4 * q + r] = qp; }
    }
    __syncthreads();

    #pragma unroll
    for (int r = 0; r < 4; r++) {
        const int row = 4 * q + r;
        const float s  = ps[0][row] + ps[1][row] + ps[2][row] + ps[3][row];
        const float qq = pq[0][row] + pq[1][row] + pq[2][row] + pq[3][row];
        const float mu  = s * (1.f / CC);
        const float var = qq * (1.f / CC) - mu * mu;
        const float rs  = rsqrtf(var + 1e-5f);
        const size_t grow = p0 + row;
        #pragma unroll
        for (int t = 0; t < 3; t++) {
            const int col = 48 * w + 16 * t + n15;
            out[grow * CC + col] = x2[grow * CC + col]
                                 + (acc2[t][r] - mu) * rs * r2w[col] + r2b[col];
        }
    }
}

extern "C" void kernel_launch(void* const* d_in, const int* in_sizes, int n_in,
                              void* d_out, int out_size, void* d_ws, size_t ws_size,
                              hipStream_t stream) {
    const float* x      = (const float*)d_in[0];
    const float* n1w    = (const float*)d_in[1];
    const float* n1b    = (const float*)d_in[2];
    const float* n2w    = (const float*)d_in[3];
    const float* n2b    = (const float*)d_in[4];
    const float* rpn1w  = (const float*)d_in[5];
    const float* rpn1b  = (const float*)d_in[6];
    const float* rpn2w  = (const float*)d_in[7];
    const float* rpn2b  = (const float*)d_in[8];
    const float* inpw   = (const float*)d_in[9];
    const float* inpb   = (const float*)d_in[10];
    const float* dww    = (const float*)d_in[11];
    const float* dwb    = (const float*)d_in[12];
    const float* dwlnw  = (const float*)d_in[13];
    const float* dwlnb  = (const float*)d_in[14];
    const float* offw   = (const float*)d_in[15];
    const float* offb   = (const float*)d_in[16];
    const float* maskw  = (const float*)d_in[17];
    const float* maskb  = (const float*)d_in[18];
    const float* cfsw   = (const float*)d_in[19];
    const float* cfsb   = (const float*)d_in[20];
    const float* outpw  = (const float*)d_in[21];
    const float* outpb  = (const float*)d_in[22];
    const float* fc1w   = (const float*)d_in[23];
    const float* fc1b   = (const float*)d_in[24];
    const float* fc2w   = (const float*)d_in[25];
    const float* fc2b   = (const float*)d_in[26];

    const int N = NPIX;                       // 12544
    const size_t NP = (size_t)N * CC;
    float* F0 = (float*)d_ws;                 // xn -> blended
    float* F1 = F0 + NP;                      // xp -> x2
    float* F2 = F1 + NP;                      // off
    float* F3 = F2 + NP;                      // x1 -> xn2
    float* Fm = F3 + NP;                      // mask logits N*96
    bf16* wsB = (bf16*)(Fm + (size_t)N * 96); // packed bf16 weights
    const bf16* inpP = wsB;
    const bf16* omP  = wsB + 36864;
    const bf16* outP = wsB + 92160;
    const bf16* fc1P = wsB + 129024;
    const bf16* fc2P = wsB + 276480;

    const int lnG = N / 4;     // 3136
    const int g16 = N / 16;    // 784

    // 0. weight prep (bf16, fragment-packed)
    prep_w_k<<<576, 256, 0, stream>>>(inpw, offw, maskw, outpw, fc1w, fc2w, wsB);
    // 1. xn = LN(x, norm1)                         -> F0
    ln4_k<<<lnG, 256, 0, stream>>>(x, n1w, n1b, F0, 1e-5f);
    // 2. xp = xn @ in_proj + b                     -> F1
    gemm16_k<<<g16, 256, 0, stream>>>(F0, inpP, inpb, F1);
    // 3. x1 = gelu(LN(dwconv(xn), 1e-6))           -> F3
    dwconv_ln_gelu_k<<<lnG, 256, 0, stream>>>(F0, dww, dwb, dwlnw, dwlnb, F3);
    // 4. off -> F2, mask logits -> Fm (fused, shared A-tile)
    gemm_offmask_k<<<g16, 256, 0, stream>>>(F3, omP, offb, maskb, F2, Fm);
    // 5. blended = sample(xp, x1, off, mlog)       -> F0
    sample_k<<<lnG, 192, 0, stream>>>(F1, F3, F2, Fm, cfsw, cfsb, F0);
    // 6. x2 = x + LN(blended@out_proj+b, rpn1); xn2 = LN(x2, norm2)
    gemm_ln2_mfma_k<<<g16, 256, 0, stream>>>(F0, outP, outpb, x, rpn1w, rpn1b,
                                             n2w, n2b, F1, F3);
    // 7. out = x2 + LN(gelu(xn2@fc1)@fc2, rpn2)    -> d_out
    mlp_mfma16_k<<<g16, 256, 0, stream>>>(F3, fc1P, fc1b, fc2P, fc2b,
                                          F1, rpn2w, rpn2b, (float*)d_out);
}